// Round 2
// baseline (1658.951 us; speedup 1.0000x reference)
//
#include <hip/hip_runtime.h>
#include <hip/hip_bf16.h>

// Problem constants (fixed-shape problem)
#define NN 262144      // nodes = 4096 graphs * 64
#define EE 2097152     // edges
#define BB 4096        // graphs
constexpr int INMLP = 6144;
constexpr int HID = 2048;
constexpr int HID4 = 512;
constexpr int OUTF = 256;

typedef short s16x8 __attribute__((ext_vector_type(8)));   // 8 bf16 in 4 VGPRs
typedef float f32x4 __attribute__((ext_vector_type(4)));

__device__ __forceinline__ float lrelu(float v) { return v >= 0.f ? v : 0.01f * v; }
__device__ __forceinline__ float bf2f(short s) {
    unsigned int u = ((unsigned int)(unsigned short)s) << 16;
    return __builtin_bit_cast(float, u);
}
__device__ __forceinline__ short f2bf(float f) {   // RNE
    unsigned int u = __builtin_bit_cast(unsigned int, f);
    u = (u + 0x7fff + ((u >> 16) & 1)) >> 16;
    return (short)u;
}
__device__ __forceinline__ float f4get(const float4& v, int i) {
    return i == 0 ? v.x : (i == 1 ? v.y : (i == 2 ? v.z : v.w));
}

// ---------------- degree counting / factors ----------------
__global__ __launch_bounds__(256) void count_deg(const int* __restrict__ src, const int* __restrict__ dst,
                                                 int* __restrict__ dout, int* __restrict__ din) {
    int e = blockIdx.x * 256 + threadIdx.x;
    atomicAdd(&dout[src[e]], 1);
    atomicAdd(&din[dst[e]], 1);
}

__global__ __launch_bounds__(256) void deg_factors(const int* __restrict__ dout, const int* __restrict__ din,
                                                   float* __restrict__ ro, float* __restrict__ ri) {
    int i = blockIdx.x * 256 + threadIdx.x;
    int a = dout[i]; if (a < 1) a = 1;
    int b = din[i];  if (b < 1) b = 1;
    ro[i] = rsqrtf((float)a);
    ri[i] = rsqrtf((float)b);
}

// ---------------- scan (exclusive prefix over din counts -> CSR offsets) ----------------
__global__ __launch_bounds__(256) void scanA(const int* __restrict__ cnt, int* __restrict__ blks) {
    __shared__ int s[256];
    int t = threadIdx.x;
    int i0 = blockIdx.x * 1024 + t * 4;
    int ts = cnt[i0] + cnt[i0 + 1] + cnt[i0 + 2] + cnt[i0 + 3];
    s[t] = ts; __syncthreads();
    for (int d = 128; d > 0; d >>= 1) { if (t < d) s[t] += s[t + d]; __syncthreads(); }
    if (t == 0) blks[blockIdx.x] = s[0];
}

__global__ __launch_bounds__(256) void scanB(int* __restrict__ blks, int* __restrict__ offN) {
    __shared__ int s[256];
    int t = threadIdx.x;
    int v = blks[t]; s[t] = v; __syncthreads();
    for (int d = 1; d < 256; d <<= 1) {
        int x = (t >= d) ? s[t - d] : 0; __syncthreads();
        s[t] += x; __syncthreads();
    }
    blks[t] = s[t] - v;            // exclusive
    if (t == 255) *offN = s[255];  // total = EE
}

__global__ __launch_bounds__(256) void scanC(const int* __restrict__ cnt, const int* __restrict__ blkoff,
                                             int* __restrict__ off) {
    __shared__ int s[256];
    int t = threadIdx.x;
    int i0 = blockIdx.x * 1024 + t * 4;
    int v0 = cnt[i0], v1 = cnt[i0 + 1], v2 = cnt[i0 + 2], v3 = cnt[i0 + 3];
    int ts = v0 + v1 + v2 + v3;
    s[t] = ts; __syncthreads();
    for (int d = 1; d < 256; d <<= 1) {
        int x = (t >= d) ? s[t - d] : 0; __syncthreads();
        s[t] += x; __syncthreads();
    }
    int base = blkoff[blockIdx.x] + (s[t] - ts);
    off[i0] = base; off[i0 + 1] = base + v0; off[i0 + 2] = base + v0 + v1; off[i0 + 3] = base + v0 + v1 + v2;
}

__global__ __launch_bounds__(256) void fill_csr(const int* __restrict__ src, const int* __restrict__ dst,
                                                const float* __restrict__ ew, const int* __restrict__ off,
                                                int* __restrict__ cur, int* __restrict__ ssrc, float* __restrict__ sew) {
    int e = blockIdx.x * 256 + threadIdx.x;
    int d = dst[e];
    int p = off[d] + atomicAdd(&cur[d], 1);
    ssrc[p] = src[e];
    sew[p] = ew[e];
}

// ---------------- skinny GEMMs (row-per-thread, uniform weight loads), bf16 out ----------------
// H[row, 0:128] = bf16( (X[row, 0:64] @ W) * ro[row] )
__global__ __launch_bounds__(256) void gemm_n64(const float* __restrict__ X, const float* __restrict__ W,
                                                const float* __restrict__ ro, short* __restrict__ H) {
    const int row = blockIdx.x * 256 + threadIdx.x;
    const float4* xp = (const float4*)(X + (size_t)row * 64);
    float4 xr[16];
#pragma unroll
    for (int i = 0; i < 16; i++) xr[i] = xp[i];
    const float sc = ro[row];
    short* hp = H + (size_t)row * 128;
#pragma unroll 1
    for (int cc = 0; cc < 128; cc += 8) {
        float acc[8] = {0, 0, 0, 0, 0, 0, 0, 0};
#pragma unroll
        for (int k = 0; k < 64; k++) {
            float xv = f4get(xr[k >> 2], k & 3);
#pragma unroll
            for (int j = 0; j < 8; j++) acc[j] = fmaf(xv, W[k * 128 + cc + j], acc[j]);
        }
        s16x8 o;
#pragma unroll
        for (int j = 0; j < 8; j++) o[j] = f2bf(acc[j] * sc);
        *(s16x8*)(hp + cc) = o;
    }
}

// H[row, 0:96] = bf16( (Xbf[row, 0:128] @ W) * ro[row] )
__global__ __launch_bounds__(256) void gemm_n128(const short* __restrict__ Xb, const float* __restrict__ W,
                                                 const float* __restrict__ ro, short* __restrict__ H) {
    const int row = blockIdx.x * 256 + threadIdx.x;
    const s16x8* xp = (const s16x8*)(Xb + (size_t)row * 128);
    float xr[128];
#pragma unroll
    for (int i = 0; i < 16; i++) {
        s16x8 v = xp[i];
#pragma unroll
        for (int j = 0; j < 8; j++) xr[i * 8 + j] = bf2f(v[j]);
    }
    const float sc = ro[row];
    short* hp = H + (size_t)row * 96;
#pragma unroll 1
    for (int cc = 0; cc < 96; cc += 8) {
        float acc[8] = {0, 0, 0, 0, 0, 0, 0, 0};
#pragma unroll
        for (int k = 0; k < 128; k++) {
            float xv = xr[k];
#pragma unroll
            for (int j = 0; j < 8; j++) acc[j] = fmaf(xv, W[k * 96 + cc + j], acc[j]);
        }
        s16x8 o;
#pragma unroll
        for (int j = 0; j < 8; j++) o[j] = f2bf(acc[j] * sc);
        *(s16x8*)(hp + cc) = o;
    }
}

// ---------------- CSR gather-reduce: one wave per destination node (bf16 in/out, fp32 acc) ----------------
template <int C>
__global__ __launch_bounds__(256) void gather_csr(const short* __restrict__ H, const int* __restrict__ offs,
                                                  const int* __restrict__ ssrc, const float* __restrict__ sew,
                                                  short* __restrict__ Out) {
    const int lane = threadIdx.x & 63;
    int node = blockIdx.x * 4 + (threadIdx.x >> 6);
    node = __builtin_amdgcn_readfirstlane(node);
    const int s0 = offs[node], s1 = offs[node + 1];
    float a0 = 0.f, a1 = 0.f;
    for (int j = s0; j < s1; ++j) {
        const int s = ssrc[j];
        const float wgt = sew[j];
        const short* hp = H + (size_t)s * C;
        a0 = fmaf(wgt, bf2f(hp[lane]), a0);
        if (lane + 64 < C) a1 = fmaf(wgt, bf2f(hp[64 + lane]), a1);
    }
    Out[(size_t)node * C + lane] = f2bf(a0);
    if (lane + 64 < C) Out[(size_t)node * C + 64 + lane] = f2bf(a1);
}

// ---------------- fused rsqrt(deg_in)*leaky_relu + GraphNorm (per 64-node graph), bf16 in place ----------------
template <int C>
__global__ __launch_bounds__(256) void graphnorm_k(short* __restrict__ Ag, const float* __restrict__ ri,
                                                   const float* __restrict__ alpha, const float* __restrict__ gamma,
                                                   const float* __restrict__ beta) {
    __shared__ float sm[64 * C];
    __shared__ float sscale[C], sshift[C];
    const int g = blockIdx.x;
    const size_t base = (size_t)g * 64 * C;
    for (int idx = threadIdx.x; idx < 64 * C; idx += 256) {
        int i = idx / C;
        float v = bf2f(Ag[base + idx]) * ri[g * 64 + i];
        sm[idx] = lrelu(v);
    }
    __syncthreads();
    if (threadIdx.x < C) {
        int c = threadIdx.x;
        float s1 = 0.f, s2 = 0.f;
#pragma unroll
        for (int i = 0; i < 64; i++) { float v = sm[i * C + c]; s1 += v; s2 += v * v; }
        float m = s1 * (1.f / 64.f);
        float a = alpha[c];
        float var = s2 * (1.f / 64.f) - m * m * a * (2.f - a);   // E[(v-am)^2]
        float sc = gamma[c] * rsqrtf(var + 1e-5f);
        sscale[c] = sc;
        sshift[c] = beta[c] - sc * a * m;
    }
    __syncthreads();
    for (int idx = threadIdx.x; idx < 64 * C; idx += 256) {
        int c = idx % C;
        Ag[base + idx] = f2bf(sscale[c] * sm[idx] + sshift[c]);
    }
}

// ---------------- Win fp32 (6144x2048) -> WinT bf16 (2048x6144), tiled transpose ----------------
__global__ __launch_bounds__(256) void transp_cvt(const float* __restrict__ W, short* __restrict__ WT) {
    __shared__ short tile[32][33];
    const int bn = blockIdx.x * 32;   // n (col of W)
    const int bk = blockIdx.y * 32;   // k (row of W)
    const int tx = threadIdx.x & 31, ty = threadIdx.x >> 5;   // 32 x 8
#pragma unroll
    for (int i = 0; i < 32; i += 8)
        tile[ty + i][tx] = f2bf(W[(size_t)(bk + ty + i) * HID + bn + tx]);
    __syncthreads();
#pragma unroll
    for (int i = 0; i < 32; i += 8)
        WT[(size_t)(bn + ty + i) * INMLP + bk + tx] = tile[tx][ty + i];
}

// ---------------- MLP1: bf16 MFMA GEMM 4096x2048x6144, fused leaky, fp32 out ----------------
// A: 4096 x 6144 bf16 row-major (gn2).  BT: 2048 x 6144 bf16 row-major (Win^T).  C: 4096 x 2048 fp32.
__global__ __launch_bounds__(256) void mlp1_mfma(const short* __restrict__ A, const short* __restrict__ BT,
                                                 float* __restrict__ C) {
    constexpr int K = INMLP, Nn = HID;
    __shared__ short As[128][40];   // 32 k + 8 pad (stride 80B -> balanced banks)
    __shared__ short Bs[128][40];
    const int t = threadIdx.x;
    const int bm = blockIdx.x * 128, bn = blockIdx.y * 128;
    const int wave = t >> 6, lane = t & 63;
    const int wm = (wave & 1) * 64, wn = (wave >> 1) * 64;
    const int m16 = lane & 15, quad = lane >> 4;
    f32x4 acc[4][4] = {};
    for (int k0 = 0; k0 < K; k0 += 32) {
#pragma unroll
        for (int i = 0; i < 2; i++) {
            int c = t + 256 * i;
            int rr = c >> 2, kk = (c & 3) * 8;
            *(s16x8*)&As[rr][kk] = *(const s16x8*)&A[(size_t)(bm + rr) * K + k0 + kk];
            *(s16x8*)&Bs[rr][kk] = *(const s16x8*)&BT[(size_t)(bn + rr) * K + k0 + kk];
        }
        __syncthreads();
        s16x8 af[4], bfr[4];
#pragma unroll
        for (int mt = 0; mt < 4; mt++) af[mt] = *(const s16x8*)&As[wm + mt * 16 + m16][quad * 8];
#pragma unroll
        for (int nt = 0; nt < 4; nt++) bfr[nt] = *(const s16x8*)&Bs[wn + nt * 16 + m16][quad * 8];
#pragma unroll
        for (int mt = 0; mt < 4; mt++)
#pragma unroll
            for (int nt = 0; nt < 4; nt++)
                acc[mt][nt] = __builtin_amdgcn_mfma_f32_16x16x32_bf16(af[mt], bfr[nt], acc[mt][nt], 0, 0, 0);
        __syncthreads();
    }
#pragma unroll
    for (int mt = 0; mt < 4; mt++)
#pragma unroll
        for (int nt = 0; nt < 4; nt++)
#pragma unroll
            for (int r4 = 0; r4 < 4; r4++) {
                int row = bm + wm + mt * 16 + quad * 4 + r4;
                int col = bn + wn + nt * 16 + m16;
                C[(size_t)row * Nn + col] = lrelu(acc[mt][nt][r4]);
            }
}

// ---------------- tiled fp32 GEMM (small MLP layers), optional fused leaky ----------------
template <int BM, int BN, int BK, int TM, int TN, bool LEAKY>
__global__ __launch_bounds__(256) void gemm_tile(const float* __restrict__ A, const float* __restrict__ B,
                                                 float* __restrict__ C, int M, int Nn, int K) {
    __shared__ float As[BK][BM + 4];
    __shared__ float Bs[BK][BN];
    const int t = threadIdx.x;
    const int bm = blockIdx.x * BM, bn = blockIdx.y * BN;
    const int tx = t % (BN / TN), ty = t / (BN / TN);
    float acc[TM][TN] = {};
    for (int k0 = 0; k0 < K; k0 += BK) {
        for (int i = t; i < BM * BK / 4; i += 256) {
            int kq = (i % (BK / 4)) * 4, m = i / (BK / 4);
            float4 v = *(const float4*)&A[(size_t)(bm + m) * K + k0 + kq];
            As[kq + 0][m] = v.x; As[kq + 1][m] = v.y; As[kq + 2][m] = v.z; As[kq + 3][m] = v.w;
        }
        for (int i = t; i < BK * BN / 4; i += 256) {
            int nq = (i % (BN / 4)) * 4, kk = i / (BN / 4);
            *(float4*)&Bs[kk][nq] = *(const float4*)&B[(size_t)(k0 + kk) * Nn + bn + nq];
        }
        __syncthreads();
#pragma unroll
        for (int kk = 0; kk < BK; kk++) {
            float ar[TM], br[TN];
#pragma unroll
            for (int i = 0; i < TM; i++) ar[i] = As[kk][ty * TM + i];
#pragma unroll
            for (int j = 0; j < TN; j++) br[j] = Bs[kk][tx * TN + j];
#pragma unroll
            for (int i = 0; i < TM; i++)
#pragma unroll
                for (int j = 0; j < TN; j++) acc[i][j] = fmaf(ar[i], br[j], acc[i][j]);
        }
        __syncthreads();
    }
#pragma unroll
    for (int i = 0; i < TM; i++)
#pragma unroll
        for (int j = 0; j < TN; j++) {
            float v = acc[i][j];
            if (LEAKY) v = lrelu(v);
            C[(size_t)(bm + ty * TM + i) * Nn + bn + tx * TN + j] = v;
        }
}

// ---------------- per-row InstanceNorm (in place, fp32) ----------------
template <int NC>
__global__ __launch_bounds__(256) void rownorm(float* __restrict__ Y) {
    float* p = Y + (size_t)blockIdx.x * NC;
    float s1 = 0.f, s2 = 0.f;
    for (int c = threadIdx.x; c < NC; c += 256) { float v = p[c]; s1 += v; s2 += v * v; }
#pragma unroll
    for (int o = 32; o > 0; o >>= 1) { s1 += __shfl_down(s1, o); s2 += __shfl_down(s2, o); }
    __shared__ float w1[4], w2[4];
    if ((threadIdx.x & 63) == 0) { w1[threadIdx.x >> 6] = s1; w2[threadIdx.x >> 6] = s2; }
    __syncthreads();
    s1 = w1[0] + w1[1] + w1[2] + w1[3];
    s2 = w2[0] + w2[1] + w2[2] + w2[3];
    float m = s1 * (1.f / NC);
    float inv = rsqrtf(s2 * (1.f / NC) - m * m + 1e-5f);
    for (int c = threadIdx.x; c < NC; c += 256) p[c] = (p[c] - m) * inv;
}

extern "C" void kernel_launch(void* const* d_in, const int* in_sizes, int n_in,
                              void* d_out, int out_size, void* d_ws, size_t ws_size,
                              hipStream_t stream) {
    const float* x    = (const float*)d_in[0];
    const float* ew   = (const float*)d_in[1];
    const int*   src  = (const int*)d_in[2];
    const int*   dst  = (const int*)d_in[3];
    const float* W1   = (const float*)d_in[4];
    const float* W2   = (const float*)d_in[5];
    const float* a1   = (const float*)d_in[6];
    const float* g1   = (const float*)d_in[7];
    const float* b1   = (const float*)d_in[8];
    const float* a2   = (const float*)d_in[9];
    const float* g2   = (const float*)d_in[10];
    const float* b2   = (const float*)d_in[11];
    const float* Win  = (const float*)d_in[12];
    const float* Whid = (const float*)d_in[13];
    const float* Wcls = (const float*)d_in[14];
    float* out = (float*)d_out;

    // ---- workspace layout (total ~149 MB) ----
    float* ro   = (float*)d_ws;                    // NN
    float* ri   = ro + NN;                         // NN
    int*   dout = (int*)(ri + NN);                 // NN
    int*   din  = dout + NN;                       // NN (counts, then fill cursor)
    int*   offs = din + NN;                        // NN+4
    int*   blks = offs + NN + 4;                   // 256
    int*   ssrc = blks + 256;                      // EE
    float* sew  = (float*)(ssrc + EE);             // EE
    short* Abf  = (short*)(sew + EE);              // NN*128 bf16 (h1 / h2; later overlaid)
    short* Bbf  = Abf + (size_t)NN * 128;          // NN*128 bf16 (agg1/gn1, agg2/gn2 = MLP input)
    // overlays into Abf region after gather2 (h2 dead): exactly fills NN*128*2 = 64 MiB
    short* WinT = Abf;                                                  // 2048*6144 bf16 = 25165824 B
    float* D    = (float*)((char*)Abf + 25165824);                      // 4096*2048 fp32 = 33554432 B
    float* Y2   = (float*)((char*)Abf + 25165824 + 33554432);           // 4096*512 fp32  =  8388608 B

    // 1) degrees
    hipMemsetAsync(dout, 0, NN * sizeof(int), stream);
    hipMemsetAsync(din, 0, NN * sizeof(int), stream);
    count_deg<<<EE / 256, 256, 0, stream>>>(src, dst, dout, din);
    deg_factors<<<NN / 256, 256, 0, stream>>>(dout, din, ro, ri);

    // 2) CSR by dst
    scanA<<<NN / 1024, 256, 0, stream>>>(din, blks);
    scanB<<<1, 256, 0, stream>>>(blks, offs + NN);
    scanC<<<NN / 1024, 256, 0, stream>>>(din, blks, offs);
    hipMemsetAsync(din, 0, NN * sizeof(int), stream);
    fill_csr<<<EE / 256, 256, 0, stream>>>(src, dst, ew, offs, din, ssrc, sew);

    // 3) conv layer 1
    gemm_n64<<<NN / 256, 256, 0, stream>>>(x, W1, ro, Abf);
    gather_csr<128><<<NN / 4, 256, 0, stream>>>(Abf, offs, ssrc, sew, Bbf);
    graphnorm_k<128><<<BB, 256, 0, stream>>>(Bbf, ri, a1, g1, b1);

    // 4) conv layer 2
    gemm_n128<<<NN / 256, 256, 0, stream>>>(Bbf, W2, ro, Abf);
    gather_csr<96><<<NN / 4, 256, 0, stream>>>(Abf, offs, ssrc, sew, Bbf);
    graphnorm_k<96><<<BB, 256, 0, stream>>>(Bbf, ri, a2, g2, b2);   // Bbf = MLP input (4096 x 6144 bf16)

    // 5) MLP
    transp_cvt<<<dim3(HID / 32, INMLP / 32), 256, 0, stream>>>(Win, WinT);
    mlp1_mfma<<<dim3(BB / 128, HID / 128), 256, 0, stream>>>(Bbf, WinT, D);
    rownorm<HID><<<BB, 256, 0, stream>>>(D);
    gemm_tile<128, 64, 16, 8, 4, true><<<dim3(BB / 128, HID4 / 64), 256, 0, stream>>>(D, Whid, Y2, BB, HID4, HID);
    rownorm<HID4><<<BB, 256, 0, stream>>>(Y2);
    gemm_tile<64, 64, 16, 4, 4, false><<<dim3(BB / 64, OUTF / 64), 256, 0, stream>>>(Y2, Wcls, out, BB, OUTF, HID4);
}

// Round 3
// 1444.647 us; speedup vs baseline: 1.1483x; 1.1483x over previous
//
#include <hip/hip_runtime.h>
#include <hip/hip_bf16.h>

// Problem constants (fixed-shape problem)
#define NN 262144      // nodes = 4096 graphs * 64
#define EE 2097152     // edges
#define BB 4096        // graphs
constexpr int INMLP = 6144;
constexpr int HID = 2048;
constexpr int HID4 = 512;
constexpr int OUTF = 256;

typedef short s16x8 __attribute__((ext_vector_type(8)));   // 8 bf16 in 4 VGPRs
typedef float f32x4 __attribute__((ext_vector_type(4)));

__device__ __forceinline__ float lrelu(float v) { return v >= 0.f ? v : 0.01f * v; }
__device__ __forceinline__ float bf2f(short s) {
    unsigned int u = ((unsigned int)(unsigned short)s) << 16;
    return __builtin_bit_cast(float, u);
}
__device__ __forceinline__ short f2bf(float f) {   // RNE
    unsigned int u = __builtin_bit_cast(unsigned int, f);
    u = (u + 0x7fff + ((u >> 16) & 1)) >> 16;
    return (short)u;
}
__device__ __forceinline__ float f4get(const float4& v, int i) {
    return i == 0 ? v.x : (i == 1 ? v.y : (i == 2 ? v.z : v.w));
}

// ---------------- degree counting / factors ----------------
__global__ __launch_bounds__(256) void count_deg(const int* __restrict__ src, const int* __restrict__ dst,
                                                 int* __restrict__ dout, int* __restrict__ din) {
    int e = blockIdx.x * 256 + threadIdx.x;
    atomicAdd(&dout[src[e]], 1);
    atomicAdd(&din[dst[e]], 1);
}

__global__ __launch_bounds__(256) void deg_factors(const int* __restrict__ dout, const int* __restrict__ din,
                                                   float* __restrict__ ro, float* __restrict__ ri) {
    int i = blockIdx.x * 256 + threadIdx.x;
    int a = dout[i]; if (a < 1) a = 1;
    int b = din[i];  if (b < 1) b = 1;
    ro[i] = rsqrtf((float)a);
    ri[i] = rsqrtf((float)b);
}

// ---------------- scan (exclusive prefix over din counts -> CSR offsets) ----------------
__global__ __launch_bounds__(256) void scanA(const int* __restrict__ cnt, int* __restrict__ blks) {
    __shared__ int s[256];
    int t = threadIdx.x;
    int i0 = blockIdx.x * 1024 + t * 4;
    int ts = cnt[i0] + cnt[i0 + 1] + cnt[i0 + 2] + cnt[i0 + 3];
    s[t] = ts; __syncthreads();
    for (int d = 128; d > 0; d >>= 1) { if (t < d) s[t] += s[t + d]; __syncthreads(); }
    if (t == 0) blks[blockIdx.x] = s[0];
}

__global__ __launch_bounds__(256) void scanB(int* __restrict__ blks, int* __restrict__ offN) {
    __shared__ int s[256];
    int t = threadIdx.x;
    int v = blks[t]; s[t] = v; __syncthreads();
    for (int d = 1; d < 256; d <<= 1) {
        int x = (t >= d) ? s[t - d] : 0; __syncthreads();
        s[t] += x; __syncthreads();
    }
    blks[t] = s[t] - v;            // exclusive
    if (t == 255) *offN = s[255];  // total = EE
}

__global__ __launch_bounds__(256) void scanC(const int* __restrict__ cnt, const int* __restrict__ blkoff,
                                             int* __restrict__ off) {
    __shared__ int s[256];
    int t = threadIdx.x;
    int i0 = blockIdx.x * 1024 + t * 4;
    int v0 = cnt[i0], v1 = cnt[i0 + 1], v2 = cnt[i0 + 2], v3 = cnt[i0 + 3];
    int ts = v0 + v1 + v2 + v3;
    s[t] = ts; __syncthreads();
    for (int d = 1; d < 256; d <<= 1) {
        int x = (t >= d) ? s[t - d] : 0; __syncthreads();
        s[t] += x; __syncthreads();
    }
    int base = blkoff[blockIdx.x] + (s[t] - ts);
    off[i0] = base; off[i0 + 1] = base + v0; off[i0 + 2] = base + v0 + v1; off[i0 + 3] = base + v0 + v1 + v2;
}

__global__ __launch_bounds__(256) void fill_csr(const int* __restrict__ src, const int* __restrict__ dst,
                                                const float* __restrict__ ew, const int* __restrict__ off,
                                                int* __restrict__ cur, int* __restrict__ ssrc, float* __restrict__ sew) {
    int e = blockIdx.x * 256 + threadIdx.x;
    int d = dst[e];
    int p = off[d] + atomicAdd(&cur[d], 1);
    ssrc[p] = src[e];
    sew[p] = ew[e];
}

// ---------------- skinny GEMMs (row-per-thread, uniform weight loads), bf16 out ----------------
// H[row, 0:128] = bf16( (X[row, 0:64] @ W) * ro[row] )
__global__ __launch_bounds__(256) void gemm_n64(const float* __restrict__ X, const float* __restrict__ W,
                                                const float* __restrict__ ro, short* __restrict__ H) {
    const int row = blockIdx.x * 256 + threadIdx.x;
    const float4* xp = (const float4*)(X + (size_t)row * 64);
    float4 xr[16];
#pragma unroll
    for (int i = 0; i < 16; i++) xr[i] = xp[i];
    const float sc = ro[row];
    short* hp = H + (size_t)row * 128;
#pragma unroll 1
    for (int cc = 0; cc < 128; cc += 8) {
        float acc[8] = {0, 0, 0, 0, 0, 0, 0, 0};
#pragma unroll
        for (int k = 0; k < 64; k++) {
            float xv = f4get(xr[k >> 2], k & 3);
#pragma unroll
            for (int j = 0; j < 8; j++) acc[j] = fmaf(xv, W[k * 128 + cc + j], acc[j]);
        }
        s16x8 o;
#pragma unroll
        for (int j = 0; j < 8; j++) o[j] = f2bf(acc[j] * sc);
        *(s16x8*)(hp + cc) = o;
    }
}

// H[row, 0:96] = bf16( (Xbf[row, 0:128] @ W) * ro[row] )
__global__ __launch_bounds__(256) void gemm_n128(const short* __restrict__ Xb, const float* __restrict__ W,
                                                 const float* __restrict__ ro, short* __restrict__ H) {
    const int row = blockIdx.x * 256 + threadIdx.x;
    const s16x8* xp = (const s16x8*)(Xb + (size_t)row * 128);
    float xr[128];
#pragma unroll
    for (int i = 0; i < 16; i++) {
        s16x8 v = xp[i];
#pragma unroll
        for (int j = 0; j < 8; j++) xr[i * 8 + j] = bf2f(v[j]);
    }
    const float sc = ro[row];
    short* hp = H + (size_t)row * 96;
#pragma unroll 1
    for (int cc = 0; cc < 96; cc += 8) {
        float acc[8] = {0, 0, 0, 0, 0, 0, 0, 0};
#pragma unroll
        for (int k = 0; k < 128; k++) {
            float xv = xr[k];
#pragma unroll
            for (int j = 0; j < 8; j++) acc[j] = fmaf(xv, W[k * 96 + cc + j], acc[j]);
        }
        s16x8 o;
#pragma unroll
        for (int j = 0; j < 8; j++) o[j] = f2bf(acc[j] * sc);
        *(s16x8*)(hp + cc) = o;
    }
}

// ---------------- CSR gather-reduce: one wave per destination node (bf16 in/out, fp32 acc) ----------------
template <int C>
__global__ __launch_bounds__(256) void gather_csr(const short* __restrict__ H, const int* __restrict__ offs,
                                                  const int* __restrict__ ssrc, const float* __restrict__ sew,
                                                  short* __restrict__ Out) {
    const int lane = threadIdx.x & 63;
    int node = blockIdx.x * 4 + (threadIdx.x >> 6);
    node = __builtin_amdgcn_readfirstlane(node);
    const int s0 = offs[node], s1 = offs[node + 1];
    float a0 = 0.f, a1 = 0.f;
    for (int j = s0; j < s1; ++j) {
        const int s = ssrc[j];
        const float wgt = sew[j];
        const short* hp = H + (size_t)s * C;
        a0 = fmaf(wgt, bf2f(hp[lane]), a0);
        if (lane + 64 < C) a1 = fmaf(wgt, bf2f(hp[64 + lane]), a1);
    }
    Out[(size_t)node * C + lane] = f2bf(a0);
    if (lane + 64 < C) Out[(size_t)node * C + 64 + lane] = f2bf(a1);
}

// ---------------- fused rsqrt(deg_in)*leaky_relu + GraphNorm (per 64-node graph), bf16 in place ----------------
template <int C>
__global__ __launch_bounds__(256) void graphnorm_k(short* __restrict__ Ag, const float* __restrict__ ri,
                                                   const float* __restrict__ alpha, const float* __restrict__ gamma,
                                                   const float* __restrict__ beta) {
    __shared__ float sm[64 * C];
    __shared__ float sscale[C], sshift[C];
    const int g = blockIdx.x;
    const size_t base = (size_t)g * 64 * C;
    for (int idx = threadIdx.x; idx < 64 * C; idx += 256) {
        int i = idx / C;
        float v = bf2f(Ag[base + idx]) * ri[g * 64 + i];
        sm[idx] = lrelu(v);
    }
    __syncthreads();
    if (threadIdx.x < C) {
        int c = threadIdx.x;
        float s1 = 0.f, s2 = 0.f;
#pragma unroll
        for (int i = 0; i < 64; i++) { float v = sm[i * C + c]; s1 += v; s2 += v * v; }
        float m = s1 * (1.f / 64.f);
        float a = alpha[c];
        float var = s2 * (1.f / 64.f) - m * m * a * (2.f - a);   // E[(v-am)^2]
        float sc = gamma[c] * rsqrtf(var + 1e-5f);
        sscale[c] = sc;
        sshift[c] = beta[c] - sc * a * m;
    }
    __syncthreads();
    for (int idx = threadIdx.x; idx < 64 * C; idx += 256) {
        int c = idx % C;
        Ag[base + idx] = f2bf(sscale[c] * sm[idx] + sshift[c]);
    }
}

// ---------------- W fp32 (R x Cc) -> WT bf16 (Cc x R), tiled transpose+convert ----------------
__global__ __launch_bounds__(256) void transp_cvt(const float* __restrict__ W, short* __restrict__ WT,
                                                  int R, int Cc) {
    __shared__ short tile[32][33];
    const int bc = blockIdx.x * 32;   // col of W
    const int br = blockIdx.y * 32;   // row of W
    const int tx = threadIdx.x & 31, ty = threadIdx.x >> 5;   // 32 x 8
#pragma unroll
    for (int i = 0; i < 32; i += 8)
        tile[ty + i][tx] = f2bf(W[(size_t)(br + ty + i) * Cc + bc + tx]);
    __syncthreads();
#pragma unroll
    for (int i = 0; i < 32; i += 8)
        WT[(size_t)(bc + ty + i) * R + br + tx] = tile[tx][ty + i];
}

// ---------------- MLP1: bf16 MFMA GEMM 4096x2048x6144, fused leaky, fp32 out ----------------
// A: 4096 x 6144 bf16 row-major (gn2).  BT: 2048 x 6144 bf16 row-major (Win^T).  C: 4096 x 2048 fp32.
__global__ __launch_bounds__(256) void mlp1_mfma(const short* __restrict__ A, const short* __restrict__ BT,
                                                 float* __restrict__ C) {
    constexpr int K = INMLP, Nn = HID;
    __shared__ short As[128][40];   // 32 k + 8 pad
    __shared__ short Bs[128][40];
    const int t = threadIdx.x;
    const int bm = blockIdx.x * 128, bn = blockIdx.y * 128;
    const int wave = t >> 6, lane = t & 63;
    const int wm = (wave & 1) * 64, wn = (wave >> 1) * 64;
    const int m16 = lane & 15, quad = lane >> 4;
    f32x4 acc[4][4] = {};
    for (int k0 = 0; k0 < K; k0 += 32) {
#pragma unroll
        for (int i = 0; i < 2; i++) {
            int c = t + 256 * i;
            int rr = c >> 2, kk = (c & 3) * 8;
            *(s16x8*)&As[rr][kk] = *(const s16x8*)&A[(size_t)(bm + rr) * K + k0 + kk];
            *(s16x8*)&Bs[rr][kk] = *(const s16x8*)&BT[(size_t)(bn + rr) * K + k0 + kk];
        }
        __syncthreads();
        s16x8 af[4], bfr[4];
#pragma unroll
        for (int mt = 0; mt < 4; mt++) af[mt] = *(const s16x8*)&As[wm + mt * 16 + m16][quad * 8];
#pragma unroll
        for (int nt = 0; nt < 4; nt++) bfr[nt] = *(const s16x8*)&Bs[wn + nt * 16 + m16][quad * 8];
#pragma unroll
        for (int mt = 0; mt < 4; mt++)
#pragma unroll
            for (int nt = 0; nt < 4; nt++)
                acc[mt][nt] = __builtin_amdgcn_mfma_f32_16x16x32_bf16(af[mt], bfr[nt], acc[mt][nt], 0, 0, 0);
        __syncthreads();
    }
#pragma unroll
    for (int mt = 0; mt < 4; mt++)
#pragma unroll
        for (int nt = 0; nt < 4; nt++)
#pragma unroll
            for (int r4 = 0; r4 < 4; r4++) {
                int row = bm + wm + mt * 16 + quad * 4 + r4;
                int col = bn + wn + nt * 16 + m16;
                C[(size_t)row * Nn + col] = lrelu(acc[mt][nt][r4]);
            }
}

// ---------------- generic MFMA GEMM: A fp32 (converted on stage), BT bf16, C fp32 ----------------
// 64x64 block tile, 4 waves, each wave 32x32 (2x2 of 16x16x32). M,N % 64 == 0, K % 32 == 0.
template <bool LEAKY>
__global__ __launch_bounds__(256) void mfma_gemm_af32(const float* __restrict__ A, const short* __restrict__ BT,
                                                      float* __restrict__ C, int M, int Nn, int K) {
    __shared__ short As[64][40];
    __shared__ short Bs[64][40];
    const int t = threadIdx.x;
    const int bm = blockIdx.x * 64, bn = blockIdx.y * 64;
    const int wave = t >> 6, lane = t & 63;
    const int wm = (wave & 1) * 32, wn = (wave >> 1) * 32;
    const int m16 = lane & 15, quad = lane >> 4;
    const int rr = t >> 2, kk = (t & 3) * 8;
    f32x4 acc[2][2] = {};
    for (int k0 = 0; k0 < K; k0 += 32) {
        const float* ap = &A[(size_t)(bm + rr) * K + k0 + kk];
        float4 v0 = *(const float4*)ap;
        float4 v1 = *(const float4*)(ap + 4);
        s16x8 a8;
        a8[0] = f2bf(v0.x); a8[1] = f2bf(v0.y); a8[2] = f2bf(v0.z); a8[3] = f2bf(v0.w);
        a8[4] = f2bf(v1.x); a8[5] = f2bf(v1.y); a8[6] = f2bf(v1.z); a8[7] = f2bf(v1.w);
        *(s16x8*)&As[rr][kk] = a8;
        *(s16x8*)&Bs[rr][kk] = *(const s16x8*)&BT[(size_t)(bn + rr) * K + k0 + kk];
        __syncthreads();
        s16x8 af[2], bfr[2];
#pragma unroll
        for (int mt = 0; mt < 2; mt++) af[mt] = *(const s16x8*)&As[wm + mt * 16 + m16][quad * 8];
#pragma unroll
        for (int nt = 0; nt < 2; nt++) bfr[nt] = *(const s16x8*)&Bs[wn + nt * 16 + m16][quad * 8];
#pragma unroll
        for (int mt = 0; mt < 2; mt++)
#pragma unroll
            for (int nt = 0; nt < 2; nt++)
                acc[mt][nt] = __builtin_amdgcn_mfma_f32_16x16x32_bf16(af[mt], bfr[nt], acc[mt][nt], 0, 0, 0);
        __syncthreads();
    }
#pragma unroll
    for (int mt = 0; mt < 2; mt++)
#pragma unroll
        for (int nt = 0; nt < 2; nt++)
#pragma unroll
            for (int r4 = 0; r4 < 4; r4++) {
                int row = bm + wm + mt * 16 + quad * 4 + r4;
                int col = bn + wn + nt * 16 + m16;
                float v = acc[mt][nt][r4];
                if (LEAKY) v = lrelu(v);
                C[(size_t)row * Nn + col] = v;
            }
}

// ---------------- per-row InstanceNorm (in place, fp32) ----------------
template <int NC>
__global__ __launch_bounds__(256) void rownorm(float* __restrict__ Y) {
    float* p = Y + (size_t)blockIdx.x * NC;
    float s1 = 0.f, s2 = 0.f;
    for (int c = threadIdx.x; c < NC; c += 256) { float v = p[c]; s1 += v; s2 += v * v; }
#pragma unroll
    for (int o = 32; o > 0; o >>= 1) { s1 += __shfl_down(s1, o); s2 += __shfl_down(s2, o); }
    __shared__ float w1[4], w2[4];
    if ((threadIdx.x & 63) == 0) { w1[threadIdx.x >> 6] = s1; w2[threadIdx.x >> 6] = s2; }
    __syncthreads();
    s1 = w1[0] + w1[1] + w1[2] + w1[3];
    s2 = w2[0] + w2[1] + w2[2] + w2[3];
    float m = s1 * (1.f / NC);
    float inv = rsqrtf(s2 * (1.f / NC) - m * m + 1e-5f);
    for (int c = threadIdx.x; c < NC; c += 256) p[c] = (p[c] - m) * inv;
}

extern "C" void kernel_launch(void* const* d_in, const int* in_sizes, int n_in,
                              void* d_out, int out_size, void* d_ws, size_t ws_size,
                              hipStream_t stream) {
    const float* x    = (const float*)d_in[0];
    const float* ew   = (const float*)d_in[1];
    const int*   src  = (const int*)d_in[2];
    const int*   dst  = (const int*)d_in[3];
    const float* W1   = (const float*)d_in[4];
    const float* W2   = (const float*)d_in[5];
    const float* a1   = (const float*)d_in[6];
    const float* g1   = (const float*)d_in[7];
    const float* b1   = (const float*)d_in[8];
    const float* a2   = (const float*)d_in[9];
    const float* g2   = (const float*)d_in[10];
    const float* b2   = (const float*)d_in[11];
    const float* Win  = (const float*)d_in[12];
    const float* Whid = (const float*)d_in[13];
    const float* Wcls = (const float*)d_in[14];
    float* out = (float*)d_out;

    // ---- workspace layout (total ~149 MB) ----
    float* ro   = (float*)d_ws;                    // NN
    float* ri   = ro + NN;                         // NN
    int*   dout = (int*)(ri + NN);                 // NN
    int*   din  = dout + NN;                       // NN (counts, then fill cursor)
    int*   offs = din + NN;                        // NN+4
    int*   blks = offs + NN + 4;                   // 256
    int*   ssrc = blks + 256;                      // EE
    float* sew  = (float*)(ssrc + EE);             // EE
    short* Abf  = (short*)(sew + EE);              // NN*128 bf16 (h1 / h2; later overlaid)
    short* Bbf  = Abf + (size_t)NN * 128;          // NN*128 bf16 (agg/gn; MLP input; later overlaid)
    // overlays into Abf region after gather2 (h2 dead): exactly fills NN*128*2 = 64 MiB
    short* WinT = Abf;                                                  // 2048*6144 bf16 = 25165824 B
    float* D    = (float*)((char*)Abf + 25165824);                      // 4096*2048 fp32 = 33554432 B
    float* Y2   = (float*)((char*)Abf + 25165824 + 33554432);           // 4096*512 fp32  =  8388608 B
    // overlays into Bbf region after mlp1_mfma consumes it:
    short* WhidT = Bbf;                            // 512*2048 bf16 = 2 MiB
    short* WclsT = WhidT + (size_t)HID4 * HID;     // 256*512 bf16 = 256 KiB

    // 1) degrees
    hipMemsetAsync(dout, 0, NN * sizeof(int), stream);
    hipMemsetAsync(din, 0, NN * sizeof(int), stream);
    count_deg<<<EE / 256, 256, 0, stream>>>(src, dst, dout, din);
    deg_factors<<<NN / 256, 256, 0, stream>>>(dout, din, ro, ri);

    // 2) CSR by dst
    scanA<<<NN / 1024, 256, 0, stream>>>(din, blks);
    scanB<<<1, 256, 0, stream>>>(blks, offs + NN);
    scanC<<<NN / 1024, 256, 0, stream>>>(din, blks, offs);
    hipMemsetAsync(din, 0, NN * sizeof(int), stream);
    fill_csr<<<EE / 256, 256, 0, stream>>>(src, dst, ew, offs, din, ssrc, sew);

    // 3) conv layer 1
    gemm_n64<<<NN / 256, 256, 0, stream>>>(x, W1, ro, Abf);
    gather_csr<128><<<NN / 4, 256, 0, stream>>>(Abf, offs, ssrc, sew, Bbf);
    graphnorm_k<128><<<BB, 256, 0, stream>>>(Bbf, ri, a1, g1, b1);

    // 4) conv layer 2
    gemm_n128<<<NN / 256, 256, 0, stream>>>(Bbf, W2, ro, Abf);
    gather_csr<96><<<NN / 4, 256, 0, stream>>>(Abf, offs, ssrc, sew, Bbf);
    graphnorm_k<96><<<BB, 256, 0, stream>>>(Bbf, ri, a2, g2, b2);   // Bbf = MLP input (4096 x 6144 bf16)

    // 5) MLP
    transp_cvt<<<dim3(HID / 32, INMLP / 32), 256, 0, stream>>>(Win, WinT, INMLP, HID);
    mlp1_mfma<<<dim3(BB / 128, HID / 128), 256, 0, stream>>>(Bbf, WinT, D);
    // Bbf now dead -> stage small transposed weights there
    transp_cvt<<<dim3(HID4 / 32, HID / 32), 256, 0, stream>>>(Whid, WhidT, HID, HID4);
    transp_cvt<<<dim3(OUTF / 32, HID4 / 32), 256, 0, stream>>>(Wcls, WclsT, HID4, OUTF);
    rownorm<HID><<<BB, 256, 0, stream>>>(D);
    mfma_gemm_af32<true><<<dim3(BB / 64, HID4 / 64), 256, 0, stream>>>(D, WhidT, Y2, BB, HID4, HID);
    rownorm<HID4><<<BB, 256, 0, stream>>>(Y2);
    mfma_gemm_af32<false><<<dim3(BB / 64, OUTF / 64), 256, 0, stream>>>(Y2, WclsT, out, BB, OUTF, HID4);
}

// Round 4
// 1164.524 us; speedup vs baseline: 1.4246x; 1.2405x over previous
//
#include <hip/hip_runtime.h>
#include <hip/hip_bf16.h>

// Problem constants (fixed-shape problem)
#define NN 262144      // nodes = 4096 graphs * 64
#define EE 2097152     // edges
#define BB 4096        // graphs
constexpr int INMLP = 6144;
constexpr int HID = 2048;
constexpr int HID4 = 512;
constexpr int OUTF = 256;

typedef short s16x8 __attribute__((ext_vector_type(8)));   // 8 bf16 in 4 VGPRs
typedef float f32x4 __attribute__((ext_vector_type(4)));

__device__ __forceinline__ float lrelu(float v) { return v >= 0.f ? v : 0.01f * v; }
__device__ __forceinline__ float bf2f(short s) {
    unsigned int u = ((unsigned int)(unsigned short)s) << 16;
    return __builtin_bit_cast(float, u);
}
__device__ __forceinline__ short f2bf(float f) {   // RNE
    unsigned int u = __builtin_bit_cast(unsigned int, f);
    u = (u + 0x7fff + ((u >> 16) & 1)) >> 16;
    return (short)u;
}

// ---------------- degree counting / factors ----------------
__global__ __launch_bounds__(256) void count_deg(const int* __restrict__ src, const int* __restrict__ dst,
                                                 int* __restrict__ dout, int* __restrict__ din) {
    int e = blockIdx.x * 256 + threadIdx.x;
    atomicAdd(&dout[src[e]], 1);
    atomicAdd(&din[dst[e]], 1);
}

__global__ __launch_bounds__(256) void deg_factors(const int* __restrict__ dout, const int* __restrict__ din,
                                                   float* __restrict__ ro, float* __restrict__ ri) {
    int i = blockIdx.x * 256 + threadIdx.x;
    int a = dout[i]; if (a < 1) a = 1;
    int b = din[i];  if (b < 1) b = 1;
    ro[i] = rsqrtf((float)a);
    ri[i] = rsqrtf((float)b);
}

// ---------------- scan (exclusive prefix over din counts -> CSR offsets) ----------------
__global__ __launch_bounds__(256) void scanA(const int* __restrict__ cnt, int* __restrict__ blks) {
    __shared__ int s[256];
    int t = threadIdx.x;
    int i0 = blockIdx.x * 1024 + t * 4;
    int ts = cnt[i0] + cnt[i0 + 1] + cnt[i0 + 2] + cnt[i0 + 3];
    s[t] = ts; __syncthreads();
    for (int d = 128; d > 0; d >>= 1) { if (t < d) s[t] += s[t + d]; __syncthreads(); }
    if (t == 0) blks[blockIdx.x] = s[0];
}

__global__ __launch_bounds__(256) void scanB(int* __restrict__ blks, int* __restrict__ offN) {
    __shared__ int s[256];
    int t = threadIdx.x;
    int v = blks[t]; s[t] = v; __syncthreads();
    for (int d = 1; d < 256; d <<= 1) {
        int x = (t >= d) ? s[t - d] : 0; __syncthreads();
        s[t] += x; __syncthreads();
    }
    blks[t] = s[t] - v;            // exclusive
    if (t == 255) *offN = s[255];  // total = EE
}

__global__ __launch_bounds__(256) void scanC(const int* __restrict__ cnt, const int* __restrict__ blkoff,
                                             int* __restrict__ off) {
    __shared__ int s[256];
    int t = threadIdx.x;
    int i0 = blockIdx.x * 1024 + t * 4;
    int v0 = cnt[i0], v1 = cnt[i0 + 1], v2 = cnt[i0 + 2], v3 = cnt[i0 + 3];
    int ts = v0 + v1 + v2 + v3;
    s[t] = ts; __syncthreads();
    for (int d = 1; d < 256; d <<= 1) {
        int x = (t >= d) ? s[t - d] : 0; __syncthreads();
        s[t] += x; __syncthreads();
    }
    int base = blkoff[blockIdx.x] + (s[t] - ts);
    off[i0] = base; off[i0 + 1] = base + v0; off[i0 + 2] = base + v0 + v1; off[i0 + 3] = base + v0 + v1 + v2;
}

__global__ __launch_bounds__(256) void fill_csr(const int* __restrict__ src, const int* __restrict__ dst,
                                                const float* __restrict__ ew, const int* __restrict__ off,
                                                int* __restrict__ cur, int* __restrict__ ssrc, float* __restrict__ sew) {
    int e = blockIdx.x * 256 + threadIdx.x;
    int d = dst[e];
    int p = off[d] + atomicAdd(&cur[d], 1);
    ssrc[p] = src[e];
    sew[p] = ew[e];
}

// ---------------- conv1: MFMA GEMM 262144x128x64.  A=x fp32, BT=W1T bf16 (128x64), out h1 bf16 scaled by ro ----------------
__global__ __launch_bounds__(256) void conv1_mfma(const float* __restrict__ X, const short* __restrict__ BT,
                                                  const float* __restrict__ ro, short* __restrict__ H) {
    __shared__ short As[128][72];   // 64 k + 8 pad
    __shared__ short Bs[128][72];
    const int t = threadIdx.x;
    const int bm = blockIdx.x * 128;
    const int wave = t >> 6, lane = t & 63;
    const int wm = (wave & 1) * 64, wn = (wave >> 1) * 64;
    const int m16 = lane & 15, quad = lane >> 4;
    // stage A: 128 rows x 64 f32 -> bf16.  thread t: row t>>1, cols (t&1)*32 .. +32
    {
        const int rr = t >> 1, c0 = (t & 1) * 32;
        const float4* xp = (const float4*)(X + (size_t)(bm + rr) * 64 + c0);
#pragma unroll
        for (int q = 0; q < 4; q++) {
            float4 v0 = xp[q * 2], v1 = xp[q * 2 + 1];
            s16x8 a8;
            a8[0] = f2bf(v0.x); a8[1] = f2bf(v0.y); a8[2] = f2bf(v0.z); a8[3] = f2bf(v0.w);
            a8[4] = f2bf(v1.x); a8[5] = f2bf(v1.y); a8[6] = f2bf(v1.z); a8[7] = f2bf(v1.w);
            *(s16x8*)&As[rr][c0 + q * 8] = a8;
        }
        // stage B: 128 n-rows x 64 k bf16
#pragma unroll
        for (int i = 0; i < 4; i++) {
            int idx = t + 256 * i;
            int nr = idx >> 3, kk = (idx & 7) * 8;
            *(s16x8*)&Bs[nr][kk] = *(const s16x8*)&BT[(size_t)nr * 64 + kk];
        }
    }
    __syncthreads();
    f32x4 acc[4][4] = {};
#pragma unroll
    for (int kc = 0; kc < 2; kc++) {
        s16x8 af[4], bfr[4];
#pragma unroll
        for (int mt = 0; mt < 4; mt++) af[mt] = *(const s16x8*)&As[wm + mt * 16 + m16][kc * 32 + quad * 8];
#pragma unroll
        for (int nt = 0; nt < 4; nt++) bfr[nt] = *(const s16x8*)&Bs[wn + nt * 16 + m16][kc * 32 + quad * 8];
#pragma unroll
        for (int mt = 0; mt < 4; mt++)
#pragma unroll
            for (int nt = 0; nt < 4; nt++)
                acc[mt][nt] = __builtin_amdgcn_mfma_f32_16x16x32_bf16(af[mt], bfr[nt], acc[mt][nt], 0, 0, 0);
    }
#pragma unroll
    for (int mt = 0; mt < 4; mt++)
#pragma unroll
        for (int r4 = 0; r4 < 4; r4++) {
            int row = bm + wm + mt * 16 + quad * 4 + r4;
            float sc = ro[row];
#pragma unroll
            for (int nt = 0; nt < 4; nt++)
                H[(size_t)row * 128 + wn + nt * 16 + m16] = f2bf(acc[mt][nt][r4] * sc);
        }
}

// ---------------- conv2: MFMA GEMM 262144x96x128.  A=gn1 bf16, BT=W2T bf16 (96x128), out h2 bf16 scaled by ro ----------------
__global__ __launch_bounds__(256) void conv2_mfma(const short* __restrict__ A, const short* __restrict__ BT,
                                                  const float* __restrict__ ro, short* __restrict__ H) {
    __shared__ short As[128][136];   // 128 k + 8 pad
    __shared__ short Bs[96][136];
    const int t = threadIdx.x;
    const int bm = blockIdx.x * 128;
    const int wave = t >> 6, lane = t & 63;
    const int wm = (wave & 1) * 64, wn = (wave >> 1) * 48;
    const int m16 = lane & 15, quad = lane >> 4;
    // stage A: 128 rows x 128 bf16
#pragma unroll
    for (int i = 0; i < 8; i++) {
        int idx = t + 256 * i;
        int rr = idx >> 4, kk = (idx & 15) * 8;
        *(s16x8*)&As[rr][kk] = *(const s16x8*)&A[(size_t)(bm + rr) * 128 + kk];
    }
    // stage B: 96 n-rows x 128 k
#pragma unroll
    for (int i = 0; i < 6; i++) {
        int idx = t + 256 * i;
        int nr = idx >> 4, kk = (idx & 15) * 8;
        *(s16x8*)&Bs[nr][kk] = *(const s16x8*)&BT[(size_t)nr * 128 + kk];
    }
    __syncthreads();
    f32x4 acc[4][3] = {};
#pragma unroll
    for (int kc = 0; kc < 4; kc++) {
        s16x8 af[4], bfr[3];
#pragma unroll
        for (int mt = 0; mt < 4; mt++) af[mt] = *(const s16x8*)&As[wm + mt * 16 + m16][kc * 32 + quad * 8];
#pragma unroll
        for (int nt = 0; nt < 3; nt++) bfr[nt] = *(const s16x8*)&Bs[wn + nt * 16 + m16][kc * 32 + quad * 8];
#pragma unroll
        for (int mt = 0; mt < 4; mt++)
#pragma unroll
            for (int nt = 0; nt < 3; nt++)
                acc[mt][nt] = __builtin_amdgcn_mfma_f32_16x16x32_bf16(af[mt], bfr[nt], acc[mt][nt], 0, 0, 0);
    }
#pragma unroll
    for (int mt = 0; mt < 4; mt++)
#pragma unroll
        for (int r4 = 0; r4 < 4; r4++) {
            int row = bm + wm + mt * 16 + quad * 4 + r4;
            float sc = ro[row];
#pragma unroll
            for (int nt = 0; nt < 3; nt++)
                H[(size_t)row * 96 + wn + nt * 16 + m16] = f2bf(acc[mt][nt][r4] * sc);
        }
}

// ---------------- CSR gather-reduce: one wave per destination node (bf16 in/out, fp32 acc) ----------------
template <int C>
__global__ __launch_bounds__(256) void gather_csr(const short* __restrict__ H, const int* __restrict__ offs,
                                                  const int* __restrict__ ssrc, const float* __restrict__ sew,
                                                  short* __restrict__ Out) {
    const int lane = threadIdx.x & 63;
    int node = blockIdx.x * 4 + (threadIdx.x >> 6);
    node = __builtin_amdgcn_readfirstlane(node);
    const int s0 = offs[node], s1 = offs[node + 1];
    float a0 = 0.f, a1 = 0.f;
    for (int j = s0; j < s1; ++j) {
        const int s = ssrc[j];
        const float wgt = sew[j];
        const short* hp = H + (size_t)s * C;
        a0 = fmaf(wgt, bf2f(hp[lane]), a0);
        if (lane + 64 < C) a1 = fmaf(wgt, bf2f(hp[64 + lane]), a1);
    }
    Out[(size_t)node * C + lane] = f2bf(a0);
    if (lane + 64 < C) Out[(size_t)node * C + 64 + lane] = f2bf(a1);
}

// ---------------- fused rsqrt(deg_in)*leaky_relu + GraphNorm (per 64-node graph), bf16 in place ----------------
template <int C>
__global__ __launch_bounds__(256) void graphnorm_k(short* __restrict__ Ag, const float* __restrict__ ri,
                                                   const float* __restrict__ alpha, const float* __restrict__ gamma,
                                                   const float* __restrict__ beta) {
    __shared__ float sm[64 * C];
    __shared__ float sscale[C], sshift[C];
    const int g = blockIdx.x;
    const size_t base = (size_t)g * 64 * C;
    for (int idx = threadIdx.x; idx < 64 * C; idx += 256) {
        int i = idx / C;
        float v = bf2f(Ag[base + idx]) * ri[g * 64 + i];
        sm[idx] = lrelu(v);
    }
    __syncthreads();
    if (threadIdx.x < C) {
        int c = threadIdx.x;
        float s1 = 0.f, s2 = 0.f;
#pragma unroll
        for (int i = 0; i < 64; i++) { float v = sm[i * C + c]; s1 += v; s2 += v * v; }
        float m = s1 * (1.f / 64.f);
        float a = alpha[c];
        float var = s2 * (1.f / 64.f) - m * m * a * (2.f - a);   // E[(v-am)^2]
        float sc = gamma[c] * rsqrtf(var + 1e-5f);
        sscale[c] = sc;
        sshift[c] = beta[c] - sc * a * m;
    }
    __syncthreads();
    for (int idx = threadIdx.x; idx < 64 * C; idx += 256) {
        int c = idx % C;
        Ag[base + idx] = f2bf(sscale[c] * sm[idx] + sshift[c]);
    }
}

// ---------------- W fp32 (R x Cc) -> WT bf16 (Cc x R), tiled transpose+convert ----------------
__global__ __launch_bounds__(256) void transp_cvt(const float* __restrict__ W, short* __restrict__ WT,
                                                  int R, int Cc) {
    __shared__ short tile[32][33];
    const int bc = blockIdx.x * 32;   // col of W
    const int br = blockIdx.y * 32;   // row of W
    const int tx = threadIdx.x & 31, ty = threadIdx.x >> 5;   // 32 x 8
#pragma unroll
    for (int i = 0; i < 32; i += 8)
        tile[ty + i][tx] = f2bf(W[(size_t)(br + ty + i) * Cc + bc + tx]);
    __syncthreads();
#pragma unroll
    for (int i = 0; i < 32; i += 8)
        WT[(size_t)(bc + ty + i) * R + br + tx] = tile[tx][ty + i];
}

// ---------------- MLP1: bf16 MFMA GEMM 4096x2048x6144, fused leaky, fp32 out ----------------
__global__ __launch_bounds__(256) void mlp1_mfma(const short* __restrict__ A, const short* __restrict__ BT,
                                                 float* __restrict__ C) {
    constexpr int K = INMLP, Nn = HID;
    __shared__ short As[128][40];   // 32 k + 8 pad
    __shared__ short Bs[128][40];
    const int t = threadIdx.x;
    const int bm = blockIdx.x * 128, bn = blockIdx.y * 128;
    const int wave = t >> 6, lane = t & 63;
    const int wm = (wave & 1) * 64, wn = (wave >> 1) * 64;
    const int m16 = lane & 15, quad = lane >> 4;
    f32x4 acc[4][4] = {};
    for (int k0 = 0; k0 < K; k0 += 32) {
#pragma unroll
        for (int i = 0; i < 2; i++) {
            int c = t + 256 * i;
            int rr = c >> 2, kk = (c & 3) * 8;
            *(s16x8*)&As[rr][kk] = *(const s16x8*)&A[(size_t)(bm + rr) * K + k0 + kk];
            *(s16x8*)&Bs[rr][kk] = *(const s16x8*)&BT[(size_t)(bn + rr) * K + k0 + kk];
        }
        __syncthreads();
        s16x8 af[4], bfr[4];
#pragma unroll
        for (int mt = 0; mt < 4; mt++) af[mt] = *(const s16x8*)&As[wm + mt * 16 + m16][quad * 8];
#pragma unroll
        for (int nt = 0; nt < 4; nt++) bfr[nt] = *(const s16x8*)&Bs[wn + nt * 16 + m16][quad * 8];
#pragma unroll
        for (int mt = 0; mt < 4; mt++)
#pragma unroll
            for (int nt = 0; nt < 4; nt++)
                acc[mt][nt] = __builtin_amdgcn_mfma_f32_16x16x32_bf16(af[mt], bfr[nt], acc[mt][nt], 0, 0, 0);
        __syncthreads();
    }
#pragma unroll
    for (int mt = 0; mt < 4; mt++)
#pragma unroll
        for (int nt = 0; nt < 4; nt++)
#pragma unroll
            for (int r4 = 0; r4 < 4; r4++) {
                int row = bm + wm + mt * 16 + quad * 4 + r4;
                int col = bn + wn + nt * 16 + m16;
                C[(size_t)row * Nn + col] = lrelu(acc[mt][nt][r4]);
            }
}

// ---------------- generic MFMA GEMM: A fp32 (converted on stage), BT bf16, C fp32 ----------------
template <bool LEAKY>
__global__ __launch_bounds__(256) void mfma_gemm_af32(const float* __restrict__ A, const short* __restrict__ BT,
                                                      float* __restrict__ C, int M, int Nn, int K) {
    __shared__ short As[64][40];
    __shared__ short Bs[64][40];
    const int t = threadIdx.x;
    const int bm = blockIdx.x * 64, bn = blockIdx.y * 64;
    const int wave = t >> 6, lane = t & 63;
    const int wm = (wave & 1) * 32, wn = (wave >> 1) * 32;
    const int m16 = lane & 15, quad = lane >> 4;
    const int rr = t >> 2, kk = (t & 3) * 8;
    f32x4 acc[2][2] = {};
    for (int k0 = 0; k0 < K; k0 += 32) {
        const float* ap = &A[(size_t)(bm + rr) * K + k0 + kk];
        float4 v0 = *(const float4*)ap;
        float4 v1 = *(const float4*)(ap + 4);
        s16x8 a8;
        a8[0] = f2bf(v0.x); a8[1] = f2bf(v0.y); a8[2] = f2bf(v0.z); a8[3] = f2bf(v0.w);
        a8[4] = f2bf(v1.x); a8[5] = f2bf(v1.y); a8[6] = f2bf(v1.z); a8[7] = f2bf(v1.w);
        *(s16x8*)&As[rr][kk] = a8;
        *(s16x8*)&Bs[rr][kk] = *(const s16x8*)&BT[(size_t)(bn + rr) * K + k0 + kk];
        __syncthreads();
        s16x8 af[2], bfr[2];
#pragma unroll
        for (int mt = 0; mt < 2; mt++) af[mt] = *(const s16x8*)&As[wm + mt * 16 + m16][quad * 8];
#pragma unroll
        for (int nt = 0; nt < 2; nt++) bfr[nt] = *(const s16x8*)&Bs[wn + nt * 16 + m16][quad * 8];
#pragma unroll
        for (int mt = 0; mt < 2; mt++)
#pragma unroll
            for (int nt = 0; nt < 2; nt++)
                acc[mt][nt] = __builtin_amdgcn_mfma_f32_16x16x32_bf16(af[mt], bfr[nt], acc[mt][nt], 0, 0, 0);
        __syncthreads();
    }
#pragma unroll
    for (int mt = 0; mt < 2; mt++)
#pragma unroll
        for (int nt = 0; nt < 2; nt++)
#pragma unroll
            for (int r4 = 0; r4 < 4; r4++) {
                int row = bm + wm + mt * 16 + quad * 4 + r4;
                int col = bn + wn + nt * 16 + m16;
                float v = acc[mt][nt][r4];
                if (LEAKY) v = lrelu(v);
                C[(size_t)row * Nn + col] = v;
            }
}

// ---------------- per-row InstanceNorm (in place, fp32) ----------------
template <int NC>
__global__ __launch_bounds__(256) void rownorm(float* __restrict__ Y) {
    float* p = Y + (size_t)blockIdx.x * NC;
    float s1 = 0.f, s2 = 0.f;
    for (int c = threadIdx.x; c < NC; c += 256) { float v = p[c]; s1 += v; s2 += v * v; }
#pragma unroll
    for (int o = 32; o > 0; o >>= 1) { s1 += __shfl_down(s1, o); s2 += __shfl_down(s2, o); }
    __shared__ float w1[4], w2[4];
    if ((threadIdx.x & 63) == 0) { w1[threadIdx.x >> 6] = s1; w2[threadIdx.x >> 6] = s2; }
    __syncthreads();
    s1 = w1[0] + w1[1] + w1[2] + w1[3];
    s2 = w2[0] + w2[1] + w2[2] + w2[3];
    float m = s1 * (1.f / NC);
    float inv = rsqrtf(s2 * (1.f / NC) - m * m + 1e-5f);
    for (int c = threadIdx.x; c < NC; c += 256) p[c] = (p[c] - m) * inv;
}

extern "C" void kernel_launch(void* const* d_in, const int* in_sizes, int n_in,
                              void* d_out, int out_size, void* d_ws, size_t ws_size,
                              hipStream_t stream) {
    const float* x    = (const float*)d_in[0];
    const float* ew   = (const float*)d_in[1];
    const int*   src  = (const int*)d_in[2];
    const int*   dst  = (const int*)d_in[3];
    const float* W1   = (const float*)d_in[4];
    const float* W2   = (const float*)d_in[5];
    const float* a1   = (const float*)d_in[6];
    const float* g1   = (const float*)d_in[7];
    const float* b1   = (const float*)d_in[8];
    const float* a2   = (const float*)d_in[9];
    const float* g2   = (const float*)d_in[10];
    const float* b2   = (const float*)d_in[11];
    const float* Win  = (const float*)d_in[12];
    const float* Whid = (const float*)d_in[13];
    const float* Wcls = (const float*)d_in[14];
    float* out = (float*)d_out;

    // ---- workspace layout (~149 MB) ----
    float* ro   = (float*)d_ws;                    // NN
    float* ri   = ro + NN;                         // NN
    int*   dout = (int*)(ri + NN);                 // NN
    int*   din  = dout + NN;                       // NN (counts, then fill cursor)
    int*   offs = din + NN;                        // NN+4
    int*   blks = offs + NN + 4;                   // 256
    short* w1t  = (short*)(blks + 256);            // 128*64 bf16
    short* w2t  = w1t + 128 * 64;                  // 96*128 bf16
    int*   ssrc = (int*)(w2t + 96 * 128);          // EE
    float* sew  = (float*)(ssrc + EE);             // EE
    short* Abf  = (short*)(sew + EE);              // NN*128 bf16 (h1 / h2; later overlaid)
    short* Bbf  = Abf + (size_t)NN * 128;          // NN*128 bf16 (agg/gn; MLP input; later overlaid)
    // overlays into Abf region after gather2 (h2 dead):
    short* WinT = Abf;                                                  // 2048*6144 bf16 = 25165824 B
    float* D    = (float*)((char*)Abf + 25165824);                      // 4096*2048 fp32 = 33554432 B
    float* Y2   = (float*)((char*)Abf + 25165824 + 33554432);           // 4096*512 fp32  =  8388608 B
    // overlays into Bbf region after mlp1_mfma consumes it:
    short* WhidT = Bbf;                            // 512*2048 bf16
    short* WclsT = WhidT + (size_t)HID4 * HID;     // 256*512 bf16

    // 1) degrees
    hipMemsetAsync(dout, 0, NN * sizeof(int), stream);
    hipMemsetAsync(din, 0, NN * sizeof(int), stream);
    count_deg<<<EE / 256, 256, 0, stream>>>(src, dst, dout, din);
    deg_factors<<<NN / 256, 256, 0, stream>>>(dout, din, ro, ri);

    // 2) CSR by dst
    scanA<<<NN / 1024, 256, 0, stream>>>(din, blks);
    scanB<<<1, 256, 0, stream>>>(blks, offs + NN);
    scanC<<<NN / 1024, 256, 0, stream>>>(din, blks, offs);
    hipMemsetAsync(din, 0, NN * sizeof(int), stream);
    fill_csr<<<EE / 256, 256, 0, stream>>>(src, dst, ew, offs, din, ssrc, sew);

    // 3) conv layer 1 (MFMA)
    transp_cvt<<<dim3(128 / 32, 64 / 32), 256, 0, stream>>>(W1, w1t, 64, 128);
    conv1_mfma<<<NN / 128, 256, 0, stream>>>(x, w1t, ro, Abf);
    gather_csr<128><<<NN / 4, 256, 0, stream>>>(Abf, offs, ssrc, sew, Bbf);
    graphnorm_k<128><<<BB, 256, 0, stream>>>(Bbf, ri, a1, g1, b1);

    // 4) conv layer 2 (MFMA)
    transp_cvt<<<dim3(96 / 32, 128 / 32), 256, 0, stream>>>(W2, w2t, 128, 96);
    conv2_mfma<<<NN / 128, 256, 0, stream>>>(Bbf, w2t, ro, Abf);
    gather_csr<96><<<NN / 4, 256, 0, stream>>>(Abf, offs, ssrc, sew, Bbf);
    graphnorm_k<96><<<BB, 256, 0, stream>>>(Bbf, ri, a2, g2, b2);   // Bbf = MLP input (4096 x 6144 bf16)

    // 5) MLP
    transp_cvt<<<dim3(HID / 32, INMLP / 32), 256, 0, stream>>>(Win, WinT, INMLP, HID);
    mlp1_mfma<<<dim3(BB / 128, HID / 128), 256, 0, stream>>>(Bbf, WinT, D);
    // Bbf now dead -> stage small transposed weights there
    transp_cvt<<<dim3(HID4 / 32, HID / 32), 256, 0, stream>>>(Whid, WhidT, HID, HID4);
    transp_cvt<<<dim3(OUTF / 32, HID4 / 32), 256, 0, stream>>>(Wcls, WclsT, HID4, OUTF);
    rownorm<HID><<<BB, 256, 0, stream>>>(D);
    mfma_gemm_af32<true><<<dim3(BB / 64, HID4 / 64), 256, 0, stream>>>(D, WhidT, Y2, BB, HID4, HID);
    rownorm<HID4><<<BB, 256, 0, stream>>>(Y2);
    mfma_gemm_af32<false><<<dim3(BB / 64, OUTF / 64), 256, 0, stream>>>(Y2, WclsT, out, BB, OUTF, HID4);
}

// Round 5
// 1130.287 us; speedup vs baseline: 1.4677x; 1.0303x over previous
//
#include <hip/hip_runtime.h>
#include <hip/hip_bf16.h>

// Problem constants (fixed-shape problem)
#define NN 262144      // nodes = 4096 graphs * 64
#define EE 2097152     // edges
#define BB 4096        // graphs
constexpr int INMLP = 6144;
constexpr int HID = 2048;
constexpr int HID4 = 512;
constexpr int OUTF = 256;

typedef short s16x8 __attribute__((ext_vector_type(8)));   // 8 bf16 in 4 VGPRs
typedef short s16x4 __attribute__((ext_vector_type(4)));
typedef float f32x4 __attribute__((ext_vector_type(4)));

__device__ __forceinline__ float lrelu(float v) { return v >= 0.f ? v : 0.01f * v; }
__device__ __forceinline__ float bf2f(short s) {
    unsigned int u = ((unsigned int)(unsigned short)s) << 16;
    return __builtin_bit_cast(float, u);
}
__device__ __forceinline__ short f2bf(float f) {   // RNE
    unsigned int u = __builtin_bit_cast(unsigned int, f);
    u = (u + 0x7fff + ((u >> 16) & 1)) >> 16;
    return (short)u;
}
// async global->LDS, 16B per lane. LDS dest = wave-uniform base + lane*16.
__device__ __forceinline__ void async16(const void* g, void* l) {
    __builtin_amdgcn_global_load_lds((__attribute__((address_space(1))) void*)g,
                                     (__attribute__((address_space(3))) void*)l, 16, 0, 0);
}

// ---------------- degree counting / factors ----------------
__global__ __launch_bounds__(256) void count_deg(const int* __restrict__ src, const int* __restrict__ dst,
                                                 int* __restrict__ dout, int* __restrict__ din) {
    int e = blockIdx.x * 256 + threadIdx.x;
    atomicAdd(&dout[src[e]], 1);
    atomicAdd(&din[dst[e]], 1);
}

__global__ __launch_bounds__(256) void deg_factors(const int* __restrict__ dout, const int* __restrict__ din,
                                                   float* __restrict__ ro, float* __restrict__ ri) {
    int i = blockIdx.x * 256 + threadIdx.x;
    int a = dout[i]; if (a < 1) a = 1;
    int b = din[i];  if (b < 1) b = 1;
    ro[i] = rsqrtf((float)a);
    ri[i] = rsqrtf((float)b);
}

// ---------------- scan (exclusive prefix over din counts -> CSR offsets) ----------------
__global__ __launch_bounds__(256) void scanA(const int* __restrict__ cnt, int* __restrict__ blks) {
    __shared__ int s[256];
    int t = threadIdx.x;
    int i0 = blockIdx.x * 1024 + t * 4;
    int ts = cnt[i0] + cnt[i0 + 1] + cnt[i0 + 2] + cnt[i0 + 3];
    s[t] = ts; __syncthreads();
    for (int d = 128; d > 0; d >>= 1) { if (t < d) s[t] += s[t + d]; __syncthreads(); }
    if (t == 0) blks[blockIdx.x] = s[0];
}

__global__ __launch_bounds__(256) void scanB(int* __restrict__ blks, int* __restrict__ offN) {
    __shared__ int s[256];
    int t = threadIdx.x;
    int v = blks[t]; s[t] = v; __syncthreads();
    for (int d = 1; d < 256; d <<= 1) {
        int x = (t >= d) ? s[t - d] : 0; __syncthreads();
        s[t] += x; __syncthreads();
    }
    blks[t] = s[t] - v;            // exclusive
    if (t == 255) *offN = s[255];  // total = EE
}

__global__ __launch_bounds__(256) void scanC(const int* __restrict__ cnt, const int* __restrict__ blkoff,
                                             int* __restrict__ off) {
    __shared__ int s[256];
    int t = threadIdx.x;
    int i0 = blockIdx.x * 1024 + t * 4;
    int v0 = cnt[i0], v1 = cnt[i0 + 1], v2 = cnt[i0 + 2], v3 = cnt[i0 + 3];
    int ts = v0 + v1 + v2 + v3;
    s[t] = ts; __syncthreads();
    for (int d = 1; d < 256; d <<= 1) {
        int x = (t >= d) ? s[t - d] : 0; __syncthreads();
        s[t] += x; __syncthreads();
    }
    int base = blkoff[blockIdx.x] + (s[t] - ts);
    off[i0] = base; off[i0 + 1] = base + v0; off[i0 + 2] = base + v0 + v1; off[i0 + 3] = base + v0 + v1 + v2;
}

// fill CSR; edge weight fused with rsqrt(deg_out)[src] (linearity: ro commutes into the sum)
__global__ __launch_bounds__(256) void fill_csr(const int* __restrict__ src, const int* __restrict__ dst,
                                                const float* __restrict__ ew, const float* __restrict__ ro,
                                                const int* __restrict__ off,
                                                int* __restrict__ cur, int* __restrict__ ssrc, float* __restrict__ sew) {
    int e = blockIdx.x * 256 + threadIdx.x;
    int d = dst[e];
    int s = src[e];
    int p = off[d] + atomicAdd(&cur[d], 1);
    ssrc[p] = s;
    sew[p] = ew[e] * ro[s];
}

// ---------------- x fp32 -> bf16 ----------------
__global__ __launch_bounds__(256) void cvt_x(const float* __restrict__ X, short* __restrict__ Xb) {
    int i = (blockIdx.x * 256 + threadIdx.x) * 4;
    float4 v = *(const float4*)(X + i);
    s16x4 o = { f2bf(v.x), f2bf(v.y), f2bf(v.z), f2bf(v.w) };
    *(s16x4*)(Xb + i) = o;
}

// ---------------- gather over 64 dims (pre-GEMM, conv1): aggx[dst] = sum sew * xb[src] ----------------
__global__ __launch_bounds__(256) void gather64(const short* __restrict__ Xb, const int* __restrict__ offs,
                                                const int* __restrict__ ssrc, const float* __restrict__ sew,
                                                short* __restrict__ Out) {
    const int lane = threadIdx.x & 63;
    int node = blockIdx.x * 4 + (threadIdx.x >> 6);
    node = __builtin_amdgcn_readfirstlane(node);
    const int s0 = offs[node], s1 = offs[node + 1];
    float a0 = 0.f;
    for (int j = s0; j < s1; ++j) {
        const int s = ssrc[j];
        const float wgt = sew[j];
        a0 = fmaf(wgt, bf2f(Xb[(size_t)s * 64 + lane]), a0);
    }
    Out[(size_t)node * 64 + lane] = f2bf(a0);
}

// ---------------- gather over 96 dims (post-GEMM, conv2) ----------------
__global__ __launch_bounds__(256) void gather96(const short* __restrict__ H, const int* __restrict__ offs,
                                                const int* __restrict__ ssrc, const float* __restrict__ sew,
                                                short* __restrict__ Out) {
    const int lane = threadIdx.x & 63;
    int node = blockIdx.x * 4 + (threadIdx.x >> 6);
    node = __builtin_amdgcn_readfirstlane(node);
    const int s0 = offs[node], s1 = offs[node + 1];
    float a0 = 0.f, a1 = 0.f;
    for (int j = s0; j < s1; ++j) {
        const int s = ssrc[j];
        const float wgt = sew[j];
        const short* hp = H + (size_t)s * 96;
        a0 = fmaf(wgt, bf2f(hp[lane]), a0);
        if (lane < 32) a1 = fmaf(wgt, bf2f(hp[64 + lane]), a1);
    }
    Out[(size_t)node * 96 + lane] = f2bf(a0);
    if (lane < 32) Out[(size_t)node * 96 + 64 + lane] = f2bf(a1);
}

// ---------------- conv1: MFMA GEMM 262144x128x64, A=aggx bf16, BT=W1T bf16 (128x64), out bf16 ----------------
__global__ __launch_bounds__(256) void conv1_mfma(const short* __restrict__ A, const short* __restrict__ BT,
                                                  short* __restrict__ H) {
    __shared__ short As[128][72];   // 64 k + 8 pad
    __shared__ short Bs[128][72];
    const int t = threadIdx.x;
    const int bm = blockIdx.x * 128;
    const int wave = t >> 6, lane = t & 63;
    const int wm = (wave & 1) * 64, wn = (wave >> 1) * 64;
    const int m16 = lane & 15, quad = lane >> 4;
#pragma unroll
    for (int i = 0; i < 4; i++) {
        int idx = t + 256 * i;
        int rr = idx >> 3, kk = (idx & 7) * 8;
        *(s16x8*)&As[rr][kk] = *(const s16x8*)&A[(size_t)(bm + rr) * 64 + kk];
        *(s16x8*)&Bs[rr][kk] = *(const s16x8*)&BT[(size_t)rr * 64 + kk];
    }
    __syncthreads();
    f32x4 acc[4][4] = {};
#pragma unroll
    for (int kc = 0; kc < 2; kc++) {
        s16x8 af[4], bfr[4];
#pragma unroll
        for (int mt = 0; mt < 4; mt++) af[mt] = *(const s16x8*)&As[wm + mt * 16 + m16][kc * 32 + quad * 8];
#pragma unroll
        for (int nt = 0; nt < 4; nt++) bfr[nt] = *(const s16x8*)&Bs[wn + nt * 16 + m16][kc * 32 + quad * 8];
#pragma unroll
        for (int mt = 0; mt < 4; mt++)
#pragma unroll
            for (int nt = 0; nt < 4; nt++)
                acc[mt][nt] = __builtin_amdgcn_mfma_f32_16x16x32_bf16(af[mt], bfr[nt], acc[mt][nt], 0, 0, 0);
    }
#pragma unroll
    for (int mt = 0; mt < 4; mt++)
#pragma unroll
        for (int r4 = 0; r4 < 4; r4++) {
            int row = bm + wm + mt * 16 + quad * 4 + r4;
#pragma unroll
            for (int nt = 0; nt < 4; nt++)
                H[(size_t)row * 128 + wn + nt * 16 + m16] = f2bf(acc[mt][nt][r4]);
        }
}

// ---------------- conv2: MFMA GEMM 262144x96x128, A=gn1 bf16, BT=W2T bf16 (96x128), out bf16 (no ro) ----------------
__global__ __launch_bounds__(256) void conv2_mfma(const short* __restrict__ A, const short* __restrict__ BT,
                                                  short* __restrict__ H) {
    __shared__ short As[128][136];   // 128 k + 8 pad
    __shared__ short Bs[96][136];
    const int t = threadIdx.x;
    const int bm = blockIdx.x * 128;
    const int wave = t >> 6, lane = t & 63;
    const int wm = (wave & 1) * 64, wn = (wave >> 1) * 48;
    const int m16 = lane & 15, quad = lane >> 4;
#pragma unroll
    for (int i = 0; i < 8; i++) {
        int idx = t + 256 * i;
        int rr = idx >> 4, kk = (idx & 15) * 8;
        *(s16x8*)&As[rr][kk] = *(const s16x8*)&A[(size_t)(bm + rr) * 128 + kk];
    }
#pragma unroll
    for (int i = 0; i < 6; i++) {
        int idx = t + 256 * i;
        int nr = idx >> 4, kk = (idx & 15) * 8;
        *(s16x8*)&Bs[nr][kk] = *(const s16x8*)&BT[(size_t)nr * 128 + kk];
    }
    __syncthreads();
    f32x4 acc[4][3] = {};
#pragma unroll
    for (int kc = 0; kc < 4; kc++) {
        s16x8 af[4], bfr[3];
#pragma unroll
        for (int mt = 0; mt < 4; mt++) af[mt] = *(const s16x8*)&As[wm + mt * 16 + m16][kc * 32 + quad * 8];
#pragma unroll
        for (int nt = 0; nt < 3; nt++) bfr[nt] = *(const s16x8*)&Bs[wn + nt * 16 + m16][kc * 32 + quad * 8];
#pragma unroll
        for (int mt = 0; mt < 4; mt++)
#pragma unroll
            for (int nt = 0; nt < 3; nt++)
                acc[mt][nt] = __builtin_amdgcn_mfma_f32_16x16x32_bf16(af[mt], bfr[nt], acc[mt][nt], 0, 0, 0);
    }
#pragma unroll
    for (int mt = 0; mt < 4; mt++)
#pragma unroll
        for (int r4 = 0; r4 < 4; r4++) {
            int row = bm + wm + mt * 16 + quad * 4 + r4;
#pragma unroll
            for (int nt = 0; nt < 3; nt++)
                H[(size_t)row * 96 + wn + nt * 16 + m16] = f2bf(acc[mt][nt][r4]);
        }
}

// ---------------- fused rsqrt(deg_in)*leaky_relu + GraphNorm (per 64-node graph), bf16 in place ----------------
template <int C>
__global__ __launch_bounds__(256) void graphnorm_k(short* __restrict__ Ag, const float* __restrict__ ri,
                                                   const float* __restrict__ alpha, const float* __restrict__ gamma,
                                                   const float* __restrict__ beta) {
    __shared__ float sm[64 * C];
    __shared__ float sscale[C], sshift[C];
    const int g = blockIdx.x;
    const size_t base = (size_t)g * 64 * C;
    for (int idx = threadIdx.x; idx < 64 * C; idx += 256) {
        int i = idx / C;
        float v = bf2f(Ag[base + idx]) * ri[g * 64 + i];
        sm[idx] = lrelu(v);
    }
    __syncthreads();
    if (threadIdx.x < C) {
        int c = threadIdx.x;
        float s1 = 0.f, s2 = 0.f;
#pragma unroll
        for (int i = 0; i < 64; i++) { float v = sm[i * C + c]; s1 += v; s2 += v * v; }
        float m = s1 * (1.f / 64.f);
        float a = alpha[c];
        float var = s2 * (1.f / 64.f) - m * m * a * (2.f - a);   // E[(v-am)^2]
        float sc = gamma[c] * rsqrtf(var + 1e-5f);
        sscale[c] = sc;
        sshift[c] = beta[c] - sc * a * m;
    }
    __syncthreads();
    for (int idx = threadIdx.x; idx < 64 * C; idx += 256) {
        int c = idx % C;
        Ag[base + idx] = f2bf(sscale[c] * sm[idx] + sshift[c]);
    }
}

// ---------------- W fp32 (R x Cc) -> WT bf16 (Cc x R), tiled transpose+convert ----------------
__global__ __launch_bounds__(256) void transp_cvt(const float* __restrict__ W, short* __restrict__ WT,
                                                  int R, int Cc) {
    __shared__ short tile[32][33];
    const int bc = blockIdx.x * 32;   // col of W
    const int br = blockIdx.y * 32;   // row of W
    const int tx = threadIdx.x & 31, ty = threadIdx.x >> 5;   // 32 x 8
#pragma unroll
    for (int i = 0; i < 32; i += 8)
        tile[ty + i][tx] = f2bf(W[(size_t)(br + ty + i) * Cc + bc + tx]);
    __syncthreads();
#pragma unroll
    for (int i = 0; i < 32; i += 8)
        WT[(size_t)(bc + ty + i) * R + br + tx] = tile[tx][ty + i];
}

// ---------------- MLP1: bf16 MFMA GEMM 4096x2048x6144, m97 recipe (global_load_lds, BK=64), fused leaky ----------------
// A: 4096 x 6144 bf16 row-major.  BT: 2048 x 6144 bf16 row-major (Win^T).  C: 4096 x 2048 fp32.
__global__ __launch_bounds__(256) void mlp1_mfma(const short* __restrict__ A, const short* __restrict__ BT,
                                                 float* __restrict__ C) {
    constexpr int K = INMLP, Nn = HID;
    __shared__ short As[128 * 64];   // unpadded: row r at offset r*64 shorts (128 B)
    __shared__ short Bs[128 * 64];
    const int t = threadIdx.x;
    const int bm = blockIdx.x * 128, bn = blockIdx.y * 128;
    const int wave = t >> 6, lane = t & 63;
    const int wm = (wave & 1) * 64, wn = (wave >> 1) * 64;
    const int m16 = lane & 15, quad = lane >> 4;
    const int lrow = lane >> 3, lcol = lane & 7;   // 8 rows x 8 chunks of 16B per issue
    f32x4 acc[4][4] = {};
    for (int k0 = 0; k0 < K; k0 += 64) {
#pragma unroll
        for (int j = 0; j < 4; j++) {
            const int rbase = 32 * wave + 8 * j;   // wave-uniform
            async16(&A[(size_t)(bm + rbase + lrow) * K + k0 + lcol * 8], &As[rbase * 64]);
            async16(&BT[(size_t)(bn + rbase + lrow) * K + k0 + lcol * 8], &Bs[rbase * 64]);
        }
        __syncthreads();
#pragma unroll
        for (int kc = 0; kc < 2; kc++) {
            s16x8 af[4], bfr[4];
#pragma unroll
            for (int mt = 0; mt < 4; mt++) af[mt] = *(const s16x8*)&As[(wm + mt * 16 + m16) * 64 + kc * 32 + quad * 8];
#pragma unroll
            for (int nt = 0; nt < 4; nt++) bfr[nt] = *(const s16x8*)&Bs[(wn + nt * 16 + m16) * 64 + kc * 32 + quad * 8];
#pragma unroll
            for (int mt = 0; mt < 4; mt++)
#pragma unroll
                for (int nt = 0; nt < 4; nt++)
                    acc[mt][nt] = __builtin_amdgcn_mfma_f32_16x16x32_bf16(af[mt], bfr[nt], acc[mt][nt], 0, 0, 0);
        }
        __syncthreads();
    }
#pragma unroll
    for (int mt = 0; mt < 4; mt++)
#pragma unroll
        for (int nt = 0; nt < 4; nt++)
#pragma unroll
            for (int r4 = 0; r4 < 4; r4++) {
                int row = bm + wm + mt * 16 + quad * 4 + r4;
                int col = bn + wn + nt * 16 + m16;
                C[(size_t)row * Nn + col] = lrelu(acc[mt][nt][r4]);
            }
}

// ---------------- generic MFMA GEMM: A fp32 (converted on stage), BT bf16, C fp32 ----------------
template <bool LEAKY>
__global__ __launch_bounds__(256) void mfma_gemm_af32(const float* __restrict__ A, const short* __restrict__ BT,
                                                      float* __restrict__ C, int M, int Nn, int K) {
    __shared__ short As[64][40];
    __shared__ short Bs[64][40];
    const int t = threadIdx.x;
    const int bm = blockIdx.x * 64, bn = blockIdx.y * 64;
    const int wave = t >> 6, lane = t & 63;
    const int wm = (wave & 1) * 32, wn = (wave >> 1) * 32;
    const int m16 = lane & 15, quad = lane >> 4;
    const int rr = t >> 2, kk = (t & 3) * 8;
    f32x4 acc[2][2] = {};
    for (int k0 = 0; k0 < K; k0 += 32) {
        const float* ap = &A[(size_t)(bm + rr) * K + k0 + kk];
        float4 v0 = *(const float4*)ap;
        float4 v1 = *(const float4*)(ap + 4);
        s16x8 a8;
        a8[0] = f2bf(v0.x); a8[1] = f2bf(v0.y); a8[2] = f2bf(v0.z); a8[3] = f2bf(v0.w);
        a8[4] = f2bf(v1.x); a8[5] = f2bf(v1.y); a8[6] = f2bf(v1.z); a8[7] = f2bf(v1.w);
        *(s16x8*)&As[rr][kk] = a8;
        *(s16x8*)&Bs[rr][kk] = *(const s16x8*)&BT[(size_t)(bn + rr) * K + k0 + kk];
        __syncthreads();
        s16x8 af[2], bfr[2];
#pragma unroll
        for (int mt = 0; mt < 2; mt++) af[mt] = *(const s16x8*)&As[wm + mt * 16 + m16][quad * 8];
#pragma unroll
        for (int nt = 0; nt < 2; nt++) bfr[nt] = *(const s16x8*)&Bs[wn + nt * 16 + m16][quad * 8];
#pragma unroll
        for (int mt = 0; mt < 2; mt++)
#pragma unroll
            for (int nt = 0; nt < 2; nt++)
                acc[mt][nt] = __builtin_amdgcn_mfma_f32_16x16x32_bf16(af[mt], bfr[nt], acc[mt][nt], 0, 0, 0);
        __syncthreads();
    }
#pragma unroll
    for (int mt = 0; mt < 2; mt++)
#pragma unroll
        for (int nt = 0; nt < 2; nt++)
#pragma unroll
            for (int r4 = 0; r4 < 4; r4++) {
                int row = bm + wm + mt * 16 + quad * 4 + r4;
                int col = bn + wn + nt * 16 + m16;
                float v = acc[mt][nt][r4];
                if (LEAKY) v = lrelu(v);
                C[(size_t)row * Nn + col] = v;
            }
}

// ---------------- per-row InstanceNorm (in place, fp32) ----------------
template <int NC>
__global__ __launch_bounds__(256) void rownorm(float* __restrict__ Y) {
    float* p = Y + (size_t)blockIdx.x * NC;
    float s1 = 0.f, s2 = 0.f;
    for (int c = threadIdx.x; c < NC; c += 256) { float v = p[c]; s1 += v; s2 += v * v; }
#pragma unroll
    for (int o = 32; o > 0; o >>= 1) { s1 += __shfl_down(s1, o); s2 += __shfl_down(s2, o); }
    __shared__ float w1[4], w2[4];
    if ((threadIdx.x & 63) == 0) { w1[threadIdx.x >> 6] = s1; w2[threadIdx.x >> 6] = s2; }
    __syncthreads();
    s1 = w1[0] + w1[1] + w1[2] + w1[3];
    s2 = w2[0] + w2[1] + w2[2] + w2[3];
    float m = s1 * (1.f / NC);
    float inv = rsqrtf(s2 * (1.f / NC) - m * m + 1e-5f);
    for (int c = threadIdx.x; c < NC; c += 256) p[c] = (p[c] - m) * inv;
}

extern "C" void kernel_launch(void* const* d_in, const int* in_sizes, int n_in,
                              void* d_out, int out_size, void* d_ws, size_t ws_size,
                              hipStream_t stream) {
    const float* x    = (const float*)d_in[0];
    const float* ew   = (const float*)d_in[1];
    const int*   src  = (const int*)d_in[2];
    const int*   dst  = (const int*)d_in[3];
    const float* W1   = (const float*)d_in[4];
    const float* W2   = (const float*)d_in[5];
    const float* a1   = (const float*)d_in[6];
    const float* g1   = (const float*)d_in[7];
    const float* b1   = (const float*)d_in[8];
    const float* a2   = (const float*)d_in[9];
    const float* g2   = (const float*)d_in[10];
    const float* b2   = (const float*)d_in[11];
    const float* Win  = (const float*)d_in[12];
    const float* Whid = (const float*)d_in[13];
    const float* Wcls = (const float*)d_in[14];
    float* out = (float*)d_out;

    // ---- workspace layout (~149 MB) ----
    float* ro   = (float*)d_ws;                    // NN
    float* ri   = ro + NN;                         // NN
    int*   dout = (int*)(ri + NN);                 // NN
    int*   din  = dout + NN;                       // NN (counts, then fill cursor)
    int*   offs = din + NN;                        // NN+4
    int*   blks = offs + NN + 4;                   // 256
    short* w1t  = (short*)(blks + 256);            // 128*64 bf16
    short* w2t  = w1t + 128 * 64;                  // 96*128 bf16
    int*   ssrc = (int*)(w2t + 96 * 128);          // EE
    float* sew  = (float*)(ssrc + EE);             // EE   (ew * ro[src])
    short* Abf  = (short*)(sew + EE);              // NN*128 bf16 region
    short* Bbf  = Abf + (size_t)NN * 128;          // NN*128 bf16 region
    // Abf region: xbf (NN*64) | aggx (NN*64); later h2 (NN*96); later MLP overlays
    short* xbf  = Abf;
    short* aggx = Abf + (size_t)NN * 64;
    // overlays into Abf region after gather2 (h2 dead):
    short* WinT = Abf;                                                  // 2048*6144 bf16 = 25165824 B
    float* D    = (float*)((char*)Abf + 25165824);                      // 4096*2048 fp32 = 33554432 B
    float* Y2   = (float*)((char*)Abf + 25165824 + 33554432);           // 4096*512 fp32  =  8388608 B
    // overlays into Bbf region after mlp1_mfma consumes it:
    short* WhidT = Bbf;                            // 512*2048 bf16
    short* WclsT = WhidT + (size_t)HID4 * HID;     // 256*512 bf16

    // 1) degrees
    hipMemsetAsync(dout, 0, NN * sizeof(int), stream);
    hipMemsetAsync(din, 0, NN * sizeof(int), stream);
    count_deg<<<EE / 256, 256, 0, stream>>>(src, dst, dout, din);
    deg_factors<<<NN / 256, 256, 0, stream>>>(dout, din, ro, ri);

    // 2) CSR by dst (edge weights fused with ro[src])
    scanA<<<NN / 1024, 256, 0, stream>>>(din, blks);
    scanB<<<1, 256, 0, stream>>>(blks, offs + NN);
    scanC<<<NN / 1024, 256, 0, stream>>>(din, blks, offs);
    hipMemsetAsync(din, 0, NN * sizeof(int), stream);
    fill_csr<<<EE / 256, 256, 0, stream>>>(src, dst, ew, ro, offs, din, ssrc, sew);

    // 3) conv layer 1: gather x first (64 dims), then GEMM
    cvt_x<<<NN * 64 / 1024, 256, 0, stream>>>(x, xbf);
    transp_cvt<<<dim3(128 / 32, 64 / 32), 256, 0, stream>>>(W1, w1t, 64, 128);
    gather64<<<NN / 4, 256, 0, stream>>>(xbf, offs, ssrc, sew, aggx);
    conv1_mfma<<<NN / 128, 256, 0, stream>>>(aggx, w1t, Bbf);
    graphnorm_k<128><<<BB, 256, 0, stream>>>(Bbf, ri, a1, g1, b1);

    // 4) conv layer 2: GEMM first (96 < 128 dims), then gather
    transp_cvt<<<dim3(96 / 32, 128 / 32), 256, 0, stream>>>(W2, w2t, 128, 96);
    conv2_mfma<<<NN / 128, 256, 0, stream>>>(Bbf, w2t, Abf);       // h2 overwrites xbf/aggx (dead)
    gather96<<<NN / 4, 256, 0, stream>>>(Abf, offs, ssrc, sew, Bbf);
    graphnorm_k<96><<<BB, 256, 0, stream>>>(Bbf, ri, a2, g2, b2);  // Bbf = MLP input (4096 x 6144 bf16)

    // 5) MLP
    transp_cvt<<<dim3(HID / 32, INMLP / 32), 256, 0, stream>>>(Win, WinT, INMLP, HID);
    mlp1_mfma<<<dim3(BB / 128, HID / 128), 256, 0, stream>>>(Bbf, WinT, D);
    // Bbf now dead -> stage small transposed weights there
    transp_cvt<<<dim3(HID4 / 32, HID / 32), 256, 0, stream>>>(Whid, WhidT, HID, HID4);
    transp_cvt<<<dim3(OUTF / 32, HID4 / 32), 256, 0, stream>>>(Wcls, WclsT, HID4, OUTF);
    rownorm<HID><<<BB, 256, 0, stream>>>(D);
    mfma_gemm_af32<true><<<dim3(BB / 64, HID4 / 64), 256, 0, stream>>>(D, WhidT, Y2, BB, HID4, HID);
    rownorm<HID4><<<BB, 256, 0, stream>>>(Y2);
    mfma_gemm_af32<false><<<dim3(BB / 64, OUTF / 64), 256, 0, stream>>>(Y2, WclsT, out, BB, OUTF, HID4);
}

// Round 7
// 1003.551 us; speedup vs baseline: 1.6531x; 1.1263x over previous
//
#include <hip/hip_runtime.h>
#include <hip/hip_bf16.h>

// Problem constants (fixed-shape problem)
#define NN 262144      // nodes = 4096 graphs * 64
#define EE 2097152     // edges
#define BB 4096        // graphs
constexpr int INMLP = 6144;
constexpr int HID = 2048;
constexpr int HID4 = 512;
constexpr int OUTF = 256;

typedef short s16x8 __attribute__((ext_vector_type(8)));   // 8 bf16 in 4 VGPRs
typedef short s16x4 __attribute__((ext_vector_type(4)));
typedef float f32x4 __attribute__((ext_vector_type(4)));

__device__ __forceinline__ float lrelu(float v) { return v >= 0.f ? v : 0.01f * v; }
__device__ __forceinline__ float bf2f(short s) {
    unsigned int u = ((unsigned int)(unsigned short)s) << 16;
    return __builtin_bit_cast(float, u);
}
__device__ __forceinline__ short f2bf(float f) {   // RNE
    unsigned int u = __builtin_bit_cast(unsigned int, f);
    u = (u + 0x7fff + ((u >> 16) & 1)) >> 16;
    return (short)u;
}
// async global->LDS, 16B per lane. LDS dest = wave-uniform base + lane*16.
__device__ __forceinline__ void async16(const void* g, void* l) {
    __builtin_amdgcn_global_load_lds((__attribute__((address_space(1))) void*)g,
                                     (__attribute__((address_space(3))) void*)l, 16, 0, 0);
}

// ---------------- degree counting / factors ----------------
__global__ __launch_bounds__(256) void count_deg(const int* __restrict__ src, const int* __restrict__ dst,
                                                 int* __restrict__ dout, int* __restrict__ din) {
    int e = blockIdx.x * 256 + threadIdx.x;
    atomicAdd(&dout[src[e]], 1);
    atomicAdd(&din[dst[e]], 1);
}

__global__ __launch_bounds__(256) void deg_factors(const int* __restrict__ dout, const int* __restrict__ din,
                                                   float* __restrict__ ro, float* __restrict__ ri) {
    int i = blockIdx.x * 256 + threadIdx.x;
    int a = dout[i]; if (a < 1) a = 1;
    int b = din[i];  if (b < 1) b = 1;
    ro[i] = rsqrtf((float)a);
    ri[i] = rsqrtf((float)b);
}

// ---------------- scan (exclusive prefix over din counts -> CSR offsets) ----------------
__global__ __launch_bounds__(256) void scanA(const int* __restrict__ cnt, int* __restrict__ blks) {
    __shared__ int s[256];
    int t = threadIdx.x;
    int i0 = blockIdx.x * 1024 + t * 4;
    int ts = cnt[i0] + cnt[i0 + 1] + cnt[i0 + 2] + cnt[i0 + 3];
    s[t] = ts; __syncthreads();
    for (int d = 128; d > 0; d >>= 1) { if (t < d) s[t] += s[t + d]; __syncthreads(); }
    if (t == 0) blks[blockIdx.x] = s[0];
}

__global__ __launch_bounds__(256) void scanB(int* __restrict__ blks, int* __restrict__ offN) {
    __shared__ int s[256];
    int t = threadIdx.x;
    int v = blks[t]; s[t] = v; __syncthreads();
    for (int d = 1; d < 256; d <<= 1) {
        int x = (t >= d) ? s[t - d] : 0; __syncthreads();
        s[t] += x; __syncthreads();
    }
    blks[t] = s[t] - v;            // exclusive
    if (t == 255) *offN = s[255];  // total = EE
}

__global__ __launch_bounds__(256) void scanC(const int* __restrict__ cnt, const int* __restrict__ blkoff,
                                             int* __restrict__ off) {
    __shared__ int s[256];
    int t = threadIdx.x;
    int i0 = blockIdx.x * 1024 + t * 4;
    int v0 = cnt[i0], v1 = cnt[i0 + 1], v2 = cnt[i0 + 2], v3 = cnt[i0 + 3];
    int ts = v0 + v1 + v2 + v3;
    s[t] = ts; __syncthreads();
    for (int d = 1; d < 256; d <<= 1) {
        int x = (t >= d) ? s[t - d] : 0; __syncthreads();
        s[t] += x; __syncthreads();
    }
    int base = blkoff[blockIdx.x] + (s[t] - ts);
    off[i0] = base; off[i0 + 1] = base + v0; off[i0 + 2] = base + v0 + v1; off[i0 + 3] = base + v0 + v1 + v2;
}

// fill CSR; edge weight fused with rsqrt(deg_out)[src] (linearity: ro commutes into the sum)
__global__ __launch_bounds__(256) void fill_csr(const int* __restrict__ src, const int* __restrict__ dst,
                                                const float* __restrict__ ew, const float* __restrict__ ro,
                                                const int* __restrict__ off,
                                                int* __restrict__ cur, int* __restrict__ ssrc, float* __restrict__ sew) {
    int e = blockIdx.x * 256 + threadIdx.x;
    int d = dst[e];
    int s = src[e];
    int p = off[d] + atomicAdd(&cur[d], 1);
    ssrc[p] = s;
    sew[p] = ew[e] * ro[s];
}

// ---------------- x fp32 -> bf16 ----------------
__global__ __launch_bounds__(256) void cvt_x(const float* __restrict__ X, short* __restrict__ Xb) {
    int i = (blockIdx.x * 256 + threadIdx.x) * 4;
    float4 v = *(const float4*)(X + i);
    s16x4 o = { f2bf(v.x), f2bf(v.y), f2bf(v.z), f2bf(v.w) };
    *(s16x4*)(Xb + i) = o;
}

// ---------------- gather 64 dims, edge-parallel: 8 edges x 8 chunks of 8 dims ----------------
__global__ __launch_bounds__(256) void gather64(const short* __restrict__ Xb, const int* __restrict__ offs,
                                                const int* __restrict__ ssrc, const float* __restrict__ sew,
                                                short* __restrict__ Out) {
    const int lane = threadIdx.x & 63;
    const int e = lane >> 3, c = lane & 7;
    int node = blockIdx.x * 4 + (threadIdx.x >> 6);
    node = __builtin_amdgcn_readfirstlane(node);
    const int s0 = offs[node], s1 = offs[node + 1];
    float acc[8] = {};
    for (int j0 = s0; j0 < s1; j0 += 8) {
        int j = j0 + e;
        bool ok = j < s1;
        int jc = ok ? j : s0;
        int s = ssrc[jc];
        float w = ok ? sew[jc] : 0.f;
        s16x8 v = *(const s16x8*)&Xb[(size_t)s * 64 + c * 8];
#pragma unroll
        for (int k = 0; k < 8; k++) acc[k] = fmaf(w, bf2f(v[k]), acc[k]);
    }
#pragma unroll
    for (int off = 8; off <= 32; off <<= 1)
#pragma unroll
        for (int k = 0; k < 8; k++) acc[k] += __shfl_xor(acc[k], off);
    if (e == 0) {
        s16x8 o;
#pragma unroll
        for (int k = 0; k < 8; k++) o[k] = f2bf(acc[k]);
        *(s16x8*)&Out[(size_t)node * 64 + c * 8] = o;
    }
}

// ---------------- conv1 + GraphNorm1 fused: MFMA 262144x128x64, block = 128 rows = 2 graphs ----------------
// Each wave's acc holds ALL 64 rows of one graph (wm = (wave&1)*64) for 64 channels, so GraphNorm
// stats reduce in-register + shfl over quad bits. LDS: staging 36864 B + scale/shift 2048 B.
__global__ __launch_bounds__(256) void conv1_gn(const short* __restrict__ A, const short* __restrict__ BT,
                                                const float* __restrict__ ri,
                                                const float* __restrict__ alpha, const float* __restrict__ gamma,
                                                const float* __restrict__ beta, short* __restrict__ Outp) {
    __shared__ short As[128][72];
    __shared__ short Bs[128][72];
    __shared__ float sscale[2][128], sshift[2][128];
    const int t = threadIdx.x;
    const int bm = blockIdx.x * 128;
    const int wave = t >> 6, lane = t & 63;
    const int wm = (wave & 1) * 64, wn = (wave >> 1) * 64;
    const int g = wave & 1;
    const int m16 = lane & 15, quad = lane >> 4;
#pragma unroll
    for (int i = 0; i < 4; i++) {
        int idx = t + 256 * i;
        int rr = idx >> 3, kk = (idx & 7) * 8;
        *(s16x8*)&As[rr][kk] = *(const s16x8*)&A[(size_t)(bm + rr) * 64 + kk];
        *(s16x8*)&Bs[rr][kk] = *(const s16x8*)&BT[(size_t)rr * 64 + kk];
    }
    __syncthreads();
    f32x4 acc[4][4] = {};
#pragma unroll
    for (int kc = 0; kc < 2; kc++) {
        s16x8 af[4], bfr[4];
#pragma unroll
        for (int mt = 0; mt < 4; mt++) af[mt] = *(const s16x8*)&As[wm + mt * 16 + m16][kc * 32 + quad * 8];
#pragma unroll
        for (int nt = 0; nt < 4; nt++) bfr[nt] = *(const s16x8*)&Bs[wn + nt * 16 + m16][kc * 32 + quad * 8];
#pragma unroll
        for (int mt = 0; mt < 4; mt++)
#pragma unroll
            for (int nt = 0; nt < 4; nt++)
                acc[mt][nt] = __builtin_amdgcn_mfma_f32_16x16x32_bf16(af[mt], bfr[nt], acc[mt][nt], 0, 0, 0);
    }
    // transform in place: v = lrelu(h1 * ri[row])
#pragma unroll
    for (int mt = 0; mt < 4; mt++)
#pragma unroll
        for (int r4 = 0; r4 < 4; r4++) {
            float rv = ri[bm + wm + mt * 16 + quad * 4 + r4];
#pragma unroll
            for (int nt = 0; nt < 4; nt++)
                acc[mt][nt][r4] = lrelu(acc[mt][nt][r4] * rv);
        }
    // per-channel stats: sum over mt,r4 (in-register) + quad (shfl_xor 16,32)
#pragma unroll
    for (int nt = 0; nt < 4; nt++) {
        float s1 = 0.f, s2 = 0.f;
#pragma unroll
        for (int mt = 0; mt < 4; mt++)
#pragma unroll
            for (int r4 = 0; r4 < 4; r4++) { float v = acc[mt][nt][r4]; s1 += v; s2 += v * v; }
        s1 += __shfl_xor(s1, 16); s1 += __shfl_xor(s1, 32);
        s2 += __shfl_xor(s2, 16); s2 += __shfl_xor(s2, 32);
        if (quad == 0) {
            int ch = wn + nt * 16 + m16;
            float m = s1 * (1.f / 64.f);
            float a = alpha[ch];
            float var = s2 * (1.f / 64.f) - m * m * a * (2.f - a);   // E[(v-am)^2]
            float sc = gamma[ch] * rsqrtf(var + 1e-5f);
            sscale[g][ch] = sc;
            sshift[g][ch] = beta[ch] - sc * a * m;
        }
    }
    __syncthreads();
#pragma unroll
    for (int nt = 0; nt < 4; nt++) {
        int ch = wn + nt * 16 + m16;
        float sc = sscale[g][ch], sh = sshift[g][ch];
#pragma unroll
        for (int mt = 0; mt < 4; mt++)
#pragma unroll
            for (int r4 = 0; r4 < 4; r4++) {
                int row = bm + wm + mt * 16 + quad * 4 + r4;
                Outp[(size_t)row * 128 + ch] = f2bf(sc * acc[mt][nt][r4] + sh);
            }
    }
}

// ---------------- conv2: MFMA GEMM 262144x96x128, A=gn1 bf16, BT=W2T bf16 (96x128), out h2 bf16 ----------------
__global__ __launch_bounds__(256) void conv2_mfma(const short* __restrict__ A, const short* __restrict__ BT,
                                                  short* __restrict__ H) {
    __shared__ short As[128][136];   // 128 k + 8 pad
    __shared__ short Bs[96][136];
    const int t = threadIdx.x;
    const int bm = blockIdx.x * 128;
    const int wave = t >> 6, lane = t & 63;
    const int wm = (wave & 1) * 64, wn = (wave >> 1) * 48;
    const int m16 = lane & 15, quad = lane >> 4;
#pragma unroll
    for (int i = 0; i < 8; i++) {
        int idx = t + 256 * i;
        int rr = idx >> 4, kk = (idx & 15) * 8;
        *(s16x8*)&As[rr][kk] = *(const s16x8*)&A[(size_t)(bm + rr) * 128 + kk];
    }
#pragma unroll
    for (int i = 0; i < 6; i++) {
        int idx = t + 256 * i;
        int nr = idx >> 4, kk = (idx & 15) * 8;
        *(s16x8*)&Bs[nr][kk] = *(const s16x8*)&BT[(size_t)nr * 128 + kk];
    }
    __syncthreads();
    f32x4 acc[4][3] = {};
#pragma unroll
    for (int kc = 0; kc < 4; kc++) {
        s16x8 af[4], bfr[3];
#pragma unroll
        for (int mt = 0; mt < 4; mt++) af[mt] = *(const s16x8*)&As[wm + mt * 16 + m16][kc * 32 + quad * 8];
#pragma unroll
        for (int nt = 0; nt < 3; nt++) bfr[nt] = *(const s16x8*)&Bs[wn + nt * 16 + m16][kc * 32 + quad * 8];
#pragma unroll
        for (int mt = 0; mt < 4; mt++)
#pragma unroll
            for (int nt = 0; nt < 3; nt++)
                acc[mt][nt] = __builtin_amdgcn_mfma_f32_16x16x32_bf16(af[mt], bfr[nt], acc[mt][nt], 0, 0, 0);
    }
#pragma unroll
    for (int mt = 0; mt < 4; mt++)
#pragma unroll
        for (int r4 = 0; r4 < 4; r4++) {
            int row = bm + wm + mt * 16 + quad * 4 + r4;
#pragma unroll
            for (int nt = 0; nt < 3; nt++)
                H[(size_t)row * 96 + wn + nt * 16 + m16] = f2bf(acc[mt][nt][r4]);
        }
}

// ---------------- gather 96 dims + GraphNorm2 fused: block = 1 graph (64 nodes) ----------------
// edge-parallel: 4 edges x 16 chunks of 6 dims per wave; wave handles 16 nodes.
__global__ __launch_bounds__(256) void gather_gn2(const short* __restrict__ H, const int* __restrict__ offs,
                                                  const int* __restrict__ ssrc, const float* __restrict__ sew,
                                                  const float* __restrict__ ri,
                                                  const float* __restrict__ alpha, const float* __restrict__ gamma,
                                                  const float* __restrict__ beta, short* __restrict__ Outp) {
    __shared__ float sm[64 * 96];
    __shared__ float sscale[96], sshift[96];
    const int g = blockIdx.x;
    const int wave = threadIdx.x >> 6, lane = threadIdx.x & 63;
    const int e = lane >> 4, c = lane & 15;
    for (int nl = wave * 16; nl < wave * 16 + 16; nl++) {
        const int node = g * 64 + nl;
        const int s0 = offs[node], s1 = offs[node + 1];
        float acc[6] = {};
        for (int j0 = s0; j0 < s1; j0 += 4) {
            int j = j0 + e;
            bool ok = j < s1;
            int jc = ok ? j : s0;
            int s = ssrc[jc];
            float w = ok ? sew[jc] : 0.f;
            const unsigned int* hp = (const unsigned int*)(H + (size_t)s * 96 + c * 6);
            unsigned int u0 = hp[0], u1 = hp[1], u2 = hp[2];
            acc[0] = fmaf(w, bf2f((short)(u0 & 0xffff)), acc[0]);
            acc[1] = fmaf(w, bf2f((short)(u0 >> 16)), acc[1]);
            acc[2] = fmaf(w, bf2f((short)(u1 & 0xffff)), acc[2]);
            acc[3] = fmaf(w, bf2f((short)(u1 >> 16)), acc[3]);
            acc[4] = fmaf(w, bf2f((short)(u2 & 0xffff)), acc[4]);
            acc[5] = fmaf(w, bf2f((short)(u2 >> 16)), acc[5]);
        }
#pragma unroll
        for (int off = 16; off <= 32; off <<= 1)
#pragma unroll
            for (int k = 0; k < 6; k++) acc[k] += __shfl_xor(acc[k], off);
        if (e == 0) {
            float rv = ri[node];
#pragma unroll
            for (int k = 0; k < 6; k++) sm[nl * 96 + c * 6 + k] = lrelu(acc[k] * rv);
        }
    }
    __syncthreads();
    if (threadIdx.x < 96) {
        int cch = threadIdx.x;
        float s1v = 0.f, s2v = 0.f;
#pragma unroll 4
        for (int i = 0; i < 64; i++) { float v = sm[i * 96 + cch]; s1v += v; s2v += v * v; }
        float m = s1v * (1.f / 64.f);
        float a = alpha[cch];
        float var = s2v * (1.f / 64.f) - m * m * a * (2.f - a);
        float sc = gamma[cch] * rsqrtf(var + 1e-5f);
        sscale[cch] = sc;
        sshift[cch] = beta[cch] - sc * a * m;
    }
    __syncthreads();
#pragma unroll
    for (int i = 0; i < 6; i++) {
        int q = threadIdx.x + 256 * i;       // 0..1535
        int nl = q / 24, cq = (q % 24) * 4;
        s16x4 o;
#pragma unroll
        for (int k = 0; k < 4; k++) o[k] = f2bf(sscale[cq + k] * sm[nl * 96 + cq + k] + sshift[cq + k]);
        *(s16x4*)&Outp[(size_t)(g * 64 + nl) * 96 + cq] = o;
    }
}

// ---------------- W fp32 (R x Cc) -> WT bf16 (Cc x R), tiled transpose+convert ----------------
__global__ __launch_bounds__(256) void transp_cvt(const float* __restrict__ W, short* __restrict__ WT,
                                                  int R, int Cc) {
    __shared__ short tile[32][33];
    const int bc = blockIdx.x * 32;   // col of W
    const int br = blockIdx.y * 32;   // row of W
    const int tx = threadIdx.x & 31, ty = threadIdx.x >> 5;   // 32 x 8
#pragma unroll
    for (int i = 0; i < 32; i += 8)
        tile[ty + i][tx] = f2bf(W[(size_t)(br + ty + i) * Cc + bc + tx]);
    __syncthreads();
#pragma unroll
    for (int i = 0; i < 32; i += 8)
        WT[(size_t)(bc + ty + i) * R + br + tx] = tile[tx][ty + i];
}

// ---------------- MLP1: bf16 MFMA GEMM 4096x2048x6144 (global_load_lds BK=64, XOR-swizzled LDS) ----------------
// Row stride in LDS is 64 shorts = 32 dwords (bank-aligned), so k-chunks are XOR-swizzled by row
// (store chunk lcol^(lrow&7), read chunk q^(row&7)) to break the 16-way ds_read bank conflict.
__global__ __launch_bounds__(256) void mlp1_mfma(const short* __restrict__ A, const short* __restrict__ BT,
                                                 float* __restrict__ C) {
    constexpr int K = INMLP, Nn = HID;
    __shared__ short As[128 * 64];
    __shared__ short Bs[128 * 64];
    const int t = threadIdx.x;
    const int bm = blockIdx.x * 128, bn = blockIdx.y * 128;
    const int wave = t >> 6, lane = t & 63;
    const int wm = (wave & 1) * 64, wn = (wave >> 1) * 64;
    const int m16 = lane & 15, quad = lane >> 4;
    const int lrow = lane >> 3, lcol = lane & 7;
    const int scol = lcol ^ (lrow & 7);        // swizzled fetch chunk
    const int xkey = m16 & 7;                  // read-side unswizzle key
    f32x4 acc[4][4] = {};
    for (int k0 = 0; k0 < K; k0 += 64) {
#pragma unroll
        for (int j = 0; j < 4; j++) {
            const int rbase = 32 * wave + 8 * j;   // wave-uniform
            async16(&A[(size_t)(bm + rbase + lrow) * K + k0 + scol * 8], &As[rbase * 64]);
            async16(&BT[(size_t)(bn + rbase + lrow) * K + k0 + scol * 8], &Bs[rbase * 64]);
        }
        __syncthreads();
#pragma unroll
        for (int kc = 0; kc < 2; kc++) {
            s16x8 af[4], bfr[4];
#pragma unroll
            for (int mt = 0; mt < 4; mt++)
                af[mt] = *(const s16x8*)&As[(wm + mt * 16 + m16) * 64 + (((kc * 4 + quad) ^ xkey)) * 8];
#pragma unroll
            for (int nt = 0; nt < 4; nt++)
                bfr[nt] = *(const s16x8*)&Bs[(wn + nt * 16 + m16) * 64 + (((kc * 4 + quad) ^ xkey)) * 8];
#pragma unroll
            for (int mt = 0; mt < 4; mt++)
#pragma unroll
                for (int nt = 0; nt < 4; nt++)
                    acc[mt][nt] = __builtin_amdgcn_mfma_f32_16x16x32_bf16(af[mt], bfr[nt], acc[mt][nt], 0, 0, 0);
        }
        __syncthreads();
    }
#pragma unroll
    for (int mt = 0; mt < 4; mt++)
#pragma unroll
        for (int nt = 0; nt < 4; nt++)
#pragma unroll
            for (int r4 = 0; r4 < 4; r4++) {
                int row = bm + wm + mt * 16 + quad * 4 + r4;
                int col = bn + wn + nt * 16 + m16;
                C[(size_t)row * Nn + col] = lrelu(acc[mt][nt][r4]);
            }
}

// ---------------- generic MFMA GEMM: A fp32 (converted on stage), BT bf16, C fp32 ----------------
template <bool LEAKY>
__global__ __launch_bounds__(256) void mfma_gemm_af32(const float* __restrict__ A, const short* __restrict__ BT,
                                                      float* __restrict__ C, int M, int Nn, int K) {
    __shared__ short As[64][40];
    __shared__ short Bs[64][40];
    const int t = threadIdx.x;
    const int bm = blockIdx.x * 64, bn = blockIdx.y * 64;
    const int wave = t >> 6, lane = t & 63;
    const int wm = (wave & 1) * 32, wn = (wave >> 1) * 32;
    const int m16 = lane & 15, quad = lane >> 4;
    const int rr = t >> 2, kk = (t & 3) * 8;
    f32x4 acc[2][2] = {};
    for (int k0 = 0; k0 < K; k0 += 32) {
        const float* ap = &A[(size_t)(bm + rr) * K + k0 + kk];
        float4 v0 = *(const float4*)ap;
        float4 v1 = *(const float4*)(ap + 4);
        s16x8 a8;
        a8[0] = f2bf(v0.x); a8[1] = f2bf(v0.y); a8[2] = f2bf(v0.z); a8[3] = f2bf(v0.w);
        a8[4] = f2bf(v1.x); a8[5] = f2bf(v1.y); a8[6] = f2bf(v1.z); a8[7] = f2bf(v1.w);
        *(s16x8*)&As[rr][kk] = a8;
        *(s16x8*)&Bs[rr][kk] = *(const s16x8*)&BT[(size_t)(bn + rr) * K + k0 + kk];
        __syncthreads();
        s16x8 af[2], bfr[2];
#pragma unroll
        for (int mt = 0; mt < 2; mt++) af[mt] = *(const s16x8*)&As[wm + mt * 16 + m16][quad * 8];
#pragma unroll
        for (int nt = 0; nt < 2; nt++) bfr[nt] = *(const s16x8*)&Bs[wn + nt * 16 + m16][quad * 8];
#pragma unroll
        for (int mt = 0; mt < 2; mt++)
#pragma unroll
            for (int nt = 0; nt < 2; nt++)
                acc[mt][nt] = __builtin_amdgcn_mfma_f32_16x16x32_bf16(af[mt], bfr[nt], acc[mt][nt], 0, 0, 0);
        __syncthreads();
    }
#pragma unroll
    for (int mt = 0; mt < 2; mt++)
#pragma unroll
        for (int nt = 0; nt < 2; nt++)
#pragma unroll
            for (int r4 = 0; r4 < 4; r4++) {
                int row = bm + wm + mt * 16 + quad * 4 + r4;
                int col = bn + wn + nt * 16 + m16;
                float v = acc[mt][nt][r4];
                if (LEAKY) v = lrelu(v);
                C[(size_t)row * Nn + col] = v;
            }
}

// ---------------- per-row InstanceNorm (in place, fp32) ----------------
template <int NC>
__global__ __launch_bounds__(256) void rownorm(float* __restrict__ Y) {
    float* p = Y + (size_t)blockIdx.x * NC;
    float s1 = 0.f, s2 = 0.f;
    for (int c = threadIdx.x; c < NC; c += 256) { float v = p[c]; s1 += v; s2 += v * v; }
#pragma unroll
    for (int o = 32; o > 0; o >>= 1) { s1 += __shfl_down(s1, o); s2 += __shfl_down(s2, o); }
    __shared__ float w1[4], w2[4];
    if ((threadIdx.x & 63) == 0) { w1[threadIdx.x >> 6] = s1; w2[threadIdx.x >> 6] = s2; }
    __syncthreads();
    s1 = w1[0] + w1[1] + w1[2] + w1[3];
    s2 = w2[0] + w2[1] + w2[2] + w2[3];
    float m = s1 * (1.f / NC);
    float inv = rsqrtf(s2 * (1.f / NC) - m * m + 1e-5f);
    for (int c = threadIdx.x; c < NC; c += 256) p[c] = (p[c] - m) * inv;
}

extern "C" void kernel_launch(void* const* d_in, const int* in_sizes, int n_in,
                              void* d_out, int out_size, void* d_ws, size_t ws_size,
                              hipStream_t stream) {
    const float* x    = (const float*)d_in[0];
    const float* ew   = (const float*)d_in[1];
    const int*   src  = (const int*)d_in[2];
    const int*   dst  = (const int*)d_in[3];
    const float* W1   = (const float*)d_in[4];
    const float* W2   = (const float*)d_in[5];
    const float* a1   = (const float*)d_in[6];
    const float* g1   = (const float*)d_in[7];
    const float* b1   = (const float*)d_in[8];
    const float* a2   = (const float*)d_in[9];
    const float* g2   = (const float*)d_in[10];
    const float* b2   = (const float*)d_in[11];
    const float* Win  = (const float*)d_in[12];
    const float* Whid = (const float*)d_in[13];
    const float* Wcls = (const float*)d_in[14];
    float* out = (float*)d_out;

    // ---- workspace layout (~149 MB) ----
    float* ro   = (float*)d_ws;                    // NN
    float* ri   = ro + NN;                         // NN
    int*   dout = (int*)(ri + NN);                 // NN
    int*   din  = dout + NN;                       // NN (counts, then fill cursor)
    int*   offs = din + NN;                        // NN+4
    int*   blks = offs + NN + 4;                   // 256
    short* w1t  = (short*)(blks + 256);            // 128*64 bf16
    short* w2t  = w1t + 128 * 64;                  // 96*128 bf16
    int*   ssrc = (int*)(w2t + 96 * 128);          // EE
    float* sew  = (float*)(ssrc + EE);             // EE   (ew * ro[src])
    short* Abf  = (short*)(sew + EE);              // NN*128 bf16 region
    short* Bbf  = Abf + (size_t)NN * 128;          // NN*128 bf16 region
    short* xbf  = Abf;                             // NN*64
    short* aggx = Abf + (size_t)NN * 64;           // NN*64
    // overlays into Abf region after gather_gn2 (h2 dead):
    short* WinT = Abf;                                                  // 2048*6144 bf16 = 25165824 B
    float* D    = (float*)((char*)Abf + 25165824);                      // 4096*2048 fp32 = 33554432 B
    float* Y2   = (float*)((char*)Abf + 25165824 + 33554432);           // 4096*512 fp32  =  8388608 B
    // overlays into Bbf region after mlp1_mfma consumes it:
    short* WhidT = Bbf;                            // 512*2048 bf16
    short* WclsT = WhidT + (size_t)HID4 * HID;     // 256*512 bf16

    // 1) degrees
    hipMemsetAsync(dout, 0, NN * sizeof(int), stream);
    hipMemsetAsync(din, 0, NN * sizeof(int), stream);
    count_deg<<<EE / 256, 256, 0, stream>>>(src, dst, dout, din);
    deg_factors<<<NN / 256, 256, 0, stream>>>(dout, din, ro, ri);

    // 2) CSR by dst (edge weights fused with ro[src])
    scanA<<<NN / 1024, 256, 0, stream>>>(din, blks);
    scanB<<<1, 256, 0, stream>>>(blks, offs + NN);
    scanC<<<NN / 1024, 256, 0, stream>>>(din, blks, offs);
    hipMemsetAsync(din, 0, NN * sizeof(int), stream);
    fill_csr<<<EE / 256, 256, 0, stream>>>(src, dst, ew, ro, offs, din, ssrc, sew);

    // 3) conv layer 1: gather x (64 dims), then GEMM + fused GraphNorm1
    cvt_x<<<NN * 64 / 1024, 256, 0, stream>>>(x, xbf);
    transp_cvt<<<dim3(128 / 32, 64 / 32), 256, 0, stream>>>(W1, w1t, 64, 128);
    gather64<<<NN / 4, 256, 0, stream>>>(xbf, offs, ssrc, sew, aggx);
    conv1_gn<<<NN / 128, 256, 0, stream>>>(aggx, w1t, ri, a1, g1, b1, Bbf);   // Bbf = gn1

    // 4) conv layer 2: GEMM, then fused gather + GraphNorm2
    transp_cvt<<<dim3(96 / 32, 128 / 32), 256, 0, stream>>>(W2, w2t, 128, 96);
    conv2_mfma<<<NN / 128, 256, 0, stream>>>(Bbf, w2t, Abf);                  // h2 (xbf/aggx dead)
    gather_gn2<<<BB, 256, 0, stream>>>(Abf, offs, ssrc, sew, ri, a2, g2, b2, Bbf);  // Bbf = gn2 (MLP input)

    // 5) MLP
    transp_cvt<<<dim3(HID / 32, INMLP / 32), 256, 0, stream>>>(Win, WinT, INMLP, HID);
    mlp1_mfma<<<dim3(BB / 128, HID / 128), 256, 0, stream>>>(Bbf, WinT, D);
    transp_cvt<<<dim3(HID4 / 32, HID / 32), 256, 0, stream>>>(Whid, WhidT, HID, HID4);
    transp_cvt<<<dim3(OUTF / 32, HID4 / 32), 256, 0, stream>>>(Wcls, WclsT, HID4, OUTF);
    rownorm<HID><<<BB, 256, 0, stream>>>(D);
    mfma_gemm_af32<true><<<dim3(BB / 64, HID4 / 64), 256, 0, stream>>>(D, WhidT, Y2, BB, HID4, HID);
    rownorm<HID4><<<BB, 256, 0, stream>>>(Y2);
    mfma_gemm_af32<false><<<dim3(BB / 64, OUTF / 64), 256, 0, stream>>>(Y2, WclsT, out, BB, OUTF, HID4);
}

// Round 8
// 967.869 us; speedup vs baseline: 1.7140x; 1.0369x over previous
//
#include <hip/hip_runtime.h>
#include <hip/hip_bf16.h>

// Problem constants (fixed-shape problem)
#define NN 262144      // nodes = 4096 graphs * 64
#define EE 2097152     // edges
#define BB 4096        // graphs
constexpr int INMLP = 6144;
constexpr int HID = 2048;
constexpr int HID4 = 512;
constexpr int OUTF = 256;

typedef short s16x8 __attribute__((ext_vector_type(8)));   // 8 bf16 in 4 VGPRs
typedef short s16x4 __attribute__((ext_vector_type(4)));
typedef float f32x4 __attribute__((ext_vector_type(4)));

__device__ __forceinline__ float lrelu(float v) { return v >= 0.f ? v : 0.01f * v; }
__device__ __forceinline__ float bf2f(short s) {
    unsigned int u = ((unsigned int)(unsigned short)s) << 16;
    return __builtin_bit_cast(float, u);
}
__device__ __forceinline__ short f2bf(float f) {   // RNE
    unsigned int u = __builtin_bit_cast(unsigned int, f);
    u = (u + 0x7fff + ((u >> 16) & 1)) >> 16;
    return (short)u;
}
// async global->LDS, 16B per lane. LDS dest = wave-uniform base + lane*16.
__device__ __forceinline__ void async16(const void* g, void* l) {
    __builtin_amdgcn_global_load_lds((__attribute__((address_space(1))) void*)g,
                                     (__attribute__((address_space(3))) void*)l, 16, 0, 0);
}
// physical XCD id (0..7) [measured: learn_hip m09 on gfx950]
__device__ __forceinline__ unsigned xcc_id() {
    unsigned x;
    asm("s_getreg_b32 %0, hwreg(HW_REG_XCC_ID)" : "=s"(x));
    return x & 7;
}

// ---------------- degree counting: XCD-replicated histograms, L2-local atomics ----------------
// All atomics to replica r come only from XCD r -> workgroup-scope (L2-cached) RMW is exact.
// Returned old value = edge's rank within (node, xcc); packed (xcc<<24)|rank for the fill pass.
__global__ __launch_bounds__(256) void count_deg(const int* __restrict__ src, const int* __restrict__ dst,
                                                 unsigned* __restrict__ dout_r, unsigned* __restrict__ din_r,
                                                 unsigned* __restrict__ rankpack) {
    const unsigned xcc = xcc_id();
    int e = blockIdx.x * 256 + threadIdx.x;
    int s = src[e], d = dst[e];
    __hip_atomic_fetch_add(&dout_r[xcc * NN + s], 1u, __ATOMIC_RELAXED, __HIP_MEMORY_SCOPE_WORKGROUP);
    unsigned r = __hip_atomic_fetch_add(&din_r[xcc * NN + d], 1u, __ATOMIC_RELAXED, __HIP_MEMORY_SCOPE_WORKGROUP);
    rankpack[e] = (xcc << 24) | r;
}

// ---------------- reduce replicas: degrees, rsqrt factors, per-(node,xcc) base offsets ----------------
__global__ __launch_bounds__(256) void deg_reduce(const unsigned* __restrict__ din_r,
                                                  const unsigned* __restrict__ dout_r,
                                                  int* __restrict__ repbase,
                                                  float* __restrict__ ro, float* __restrict__ ri,
                                                  int* __restrict__ din) {
    int i = blockIdx.x * 256 + threadIdx.x;
    unsigned run = 0, d0 = 0;
#pragma unroll
    for (int r = 0; r < 8; r++) {
        repbase[r * NN + i] = (int)run;
        run += din_r[r * NN + i];
        d0 += dout_r[r * NN + i];
    }
    din[i] = (int)run;
    ro[i] = rsqrtf((float)(d0 < 1u ? 1u : d0));
    ri[i] = rsqrtf((float)(run < 1u ? 1u : run));
}

// ---------------- scan (exclusive prefix over din counts -> CSR offsets) ----------------
__global__ __launch_bounds__(256) void scanA(const int* __restrict__ cnt, int* __restrict__ blks) {
    __shared__ int s[256];
    int t = threadIdx.x;
    int i0 = blockIdx.x * 1024 + t * 4;
    int ts = cnt[i0] + cnt[i0 + 1] + cnt[i0 + 2] + cnt[i0 + 3];
    s[t] = ts; __syncthreads();
    for (int d = 128; d > 0; d >>= 1) { if (t < d) s[t] += s[t + d]; __syncthreads(); }
    if (t == 0) blks[blockIdx.x] = s[0];
}

__global__ __launch_bounds__(256) void scanB(int* __restrict__ blks, int* __restrict__ offN) {
    __shared__ int s[256];
    int t = threadIdx.x;
    int v = blks[t]; s[t] = v; __syncthreads();
    for (int d = 1; d < 256; d <<= 1) {
        int x = (t >= d) ? s[t - d] : 0; __syncthreads();
        s[t] += x; __syncthreads();
    }
    blks[t] = s[t] - v;            // exclusive
    if (t == 255) *offN = s[255];  // total = EE
}

__global__ __launch_bounds__(256) void scanC(const int* __restrict__ cnt, const int* __restrict__ blkoff,
                                             int* __restrict__ off) {
    __shared__ int s[256];
    int t = threadIdx.x;
    int i0 = blockIdx.x * 1024 + t * 4;
    int v0 = cnt[i0], v1 = cnt[i0 + 1], v2 = cnt[i0 + 2], v3 = cnt[i0 + 3];
    int ts = v0 + v1 + v2 + v3;
    s[t] = ts; __syncthreads();
    for (int d = 1; d < 256; d <<= 1) {
        int x = (t >= d) ? s[t - d] : 0; __syncthreads();
        s[t] += x; __syncthreads();
    }
    int base = blkoff[blockIdx.x] + (s[t] - ts);
    off[i0] = base; off[i0 + 1] = base + v0; off[i0 + 2] = base + v0 + v1; off[i0 + 3] = base + v0 + v1 + v2;
}

// ---------------- fill CSR: atomic-free scatter using precomputed (xcc, rank) ----------------
// edge record = int2 { src, bf32(ew * ro[src]) }  (ro folded in by linearity)
__global__ __launch_bounds__(256) void fill_csr(const int* __restrict__ src, const int* __restrict__ dst,
                                                const float* __restrict__ ew, const float* __restrict__ ro,
                                                const int* __restrict__ off, const int* __restrict__ repbase,
                                                const unsigned* __restrict__ rankpack, int2* __restrict__ edg) {
    int e = blockIdx.x * 256 + threadIdx.x;
    int d = dst[e];
    int s = src[e];
    unsigned pk = rankpack[e];
    int xcc = pk >> 24, rank = pk & 0xffffff;
    int p = off[d] + repbase[xcc * NN + d] + rank;
    edg[p] = make_int2(s, __builtin_bit_cast(int, ew[e] * ro[s]));
}

// ---------------- x fp32 -> bf16 ----------------
__global__ __launch_bounds__(256) void cvt_x(const float* __restrict__ X, short* __restrict__ Xb) {
    int i = (blockIdx.x * 256 + threadIdx.x) * 4;
    float4 v = *(const float4*)(X + i);
    s16x4 o = { f2bf(v.x), f2bf(v.y), f2bf(v.z), f2bf(v.w) };
    *(s16x4*)(Xb + i) = o;
}

// ---------------- gather 64 dims, edge-parallel: 8 edges x 8 chunks of 8 dims ----------------
__global__ __launch_bounds__(256) void gather64(const short* __restrict__ Xb, const int* __restrict__ offs,
                                                const int2* __restrict__ edg, short* __restrict__ Out) {
    const int lane = threadIdx.x & 63;
    const int e = lane >> 3, c = lane & 7;
    int node = blockIdx.x * 4 + (threadIdx.x >> 6);
    node = __builtin_amdgcn_readfirstlane(node);
    const int s0 = offs[node], s1 = offs[node + 1];
    float acc[8] = {};
    for (int j0 = s0; j0 < s1; j0 += 8) {
        int j = j0 + e;
        bool ok = j < s1;
        int2 pe = edg[ok ? j : s0];
        int s = pe.x;
        float w = ok ? __builtin_bit_cast(float, pe.y) : 0.f;
        s16x8 v = *(const s16x8*)&Xb[(size_t)s * 64 + c * 8];
#pragma unroll
        for (int k = 0; k < 8; k++) acc[k] = fmaf(w, bf2f(v[k]), acc[k]);
    }
#pragma unroll
    for (int off = 8; off <= 32; off <<= 1)
#pragma unroll
        for (int k = 0; k < 8; k++) acc[k] += __shfl_xor(acc[k], off);
    if (e == 0) {
        s16x8 o;
#pragma unroll
        for (int k = 0; k < 8; k++) o[k] = f2bf(acc[k]);
        *(s16x8*)&Out[(size_t)node * 64 + c * 8] = o;
    }
}

// ---------------- conv1 + GraphNorm1 fused: MFMA 262144x128x64, block = 128 rows = 2 graphs ----------------
__global__ __launch_bounds__(256) void conv1_gn(const short* __restrict__ A, const short* __restrict__ BT,
                                                const float* __restrict__ ri,
                                                const float* __restrict__ alpha, const float* __restrict__ gamma,
                                                const float* __restrict__ beta, short* __restrict__ Outp) {
    __shared__ short As[128][72];
    __shared__ short Bs[128][72];
    __shared__ float sscale[2][128], sshift[2][128];
    const int t = threadIdx.x;
    const int bm = blockIdx.x * 128;
    const int wave = t >> 6, lane = t & 63;
    const int wm = (wave & 1) * 64, wn = (wave >> 1) * 64;
    const int g = wave & 1;
    const int m16 = lane & 15, quad = lane >> 4;
#pragma unroll
    for (int i = 0; i < 4; i++) {
        int idx = t + 256 * i;
        int rr = idx >> 3, kk = (idx & 7) * 8;
        *(s16x8*)&As[rr][kk] = *(const s16x8*)&A[(size_t)(bm + rr) * 64 + kk];
        *(s16x8*)&Bs[rr][kk] = *(const s16x8*)&BT[(size_t)rr * 64 + kk];
    }
    __syncthreads();
    f32x4 acc[4][4] = {};
#pragma unroll
    for (int kc = 0; kc < 2; kc++) {
        s16x8 af[4], bfr[4];
#pragma unroll
        for (int mt = 0; mt < 4; mt++) af[mt] = *(const s16x8*)&As[wm + mt * 16 + m16][kc * 32 + quad * 8];
#pragma unroll
        for (int nt = 0; nt < 4; nt++) bfr[nt] = *(const s16x8*)&Bs[wn + nt * 16 + m16][kc * 32 + quad * 8];
#pragma unroll
        for (int mt = 0; mt < 4; mt++)
#pragma unroll
            for (int nt = 0; nt < 4; nt++)
                acc[mt][nt] = __builtin_amdgcn_mfma_f32_16x16x32_bf16(af[mt], bfr[nt], acc[mt][nt], 0, 0, 0);
    }
    // transform in place: v = lrelu(h1 * ri[row])
#pragma unroll
    for (int mt = 0; mt < 4; mt++)
#pragma unroll
        for (int r4 = 0; r4 < 4; r4++) {
            float rv = ri[bm + wm + mt * 16 + quad * 4 + r4];
#pragma unroll
            for (int nt = 0; nt < 4; nt++)
                acc[mt][nt][r4] = lrelu(acc[mt][nt][r4] * rv);
        }
    // per-channel stats: sum over mt,r4 (in-register) + quad (shfl_xor 16,32)
#pragma unroll
    for (int nt = 0; nt < 4; nt++) {
        float s1 = 0.f, s2 = 0.f;
#pragma unroll
        for (int mt = 0; mt < 4; mt++)
#pragma unroll
            for (int r4 = 0; r4 < 4; r4++) { float v = acc[mt][nt][r4]; s1 += v; s2 += v * v; }
        s1 += __shfl_xor(s1, 16); s1 += __shfl_xor(s1, 32);
        s2 += __shfl_xor(s2, 16); s2 += __shfl_xor(s2, 32);
        if (quad == 0) {
            int ch = wn + nt * 16 + m16;
            float m = s1 * (1.f / 64.f);
            float a = alpha[ch];
            float var = s2 * (1.f / 64.f) - m * m * a * (2.f - a);   // E[(v-am)^2]
            float sc = gamma[ch] * rsqrtf(var + 1e-5f);
            sscale[g][ch] = sc;
            sshift[g][ch] = beta[ch] - sc * a * m;
        }
    }
    __syncthreads();
#pragma unroll
    for (int nt = 0; nt < 4; nt++) {
        int ch = wn + nt * 16 + m16;
        float sc = sscale[g][ch], sh = sshift[g][ch];
#pragma unroll
        for (int mt = 0; mt < 4; mt++)
#pragma unroll
            for (int r4 = 0; r4 < 4; r4++) {
                int row = bm + wm + mt * 16 + quad * 4 + r4;
                Outp[(size_t)row * 128 + ch] = f2bf(sc * acc[mt][nt][r4] + sh);
            }
    }
}

// ---------------- conv2: MFMA GEMM 262144x96x128, A=gn1 bf16, BT=W2T bf16 (96x128), out h2 bf16 ----------------
__global__ __launch_bounds__(256) void conv2_mfma(const short* __restrict__ A, const short* __restrict__ BT,
                                                  short* __restrict__ H) {
    __shared__ short As[128][136];   // 128 k + 8 pad
    __shared__ short Bs[96][136];
    const int t = threadIdx.x;
    const int bm = blockIdx.x * 128;
    const int wave = t >> 6, lane = t & 63;
    const int wm = (wave & 1) * 64, wn = (wave >> 1) * 48;
    const int m16 = lane & 15, quad = lane >> 4;
#pragma unroll
    for (int i = 0; i < 8; i++) {
        int idx = t + 256 * i;
        int rr = idx >> 4, kk = (idx & 15) * 8;
        *(s16x8*)&As[rr][kk] = *(const s16x8*)&A[(size_t)(bm + rr) * 128 + kk];
    }
#pragma unroll
    for (int i = 0; i < 6; i++) {
        int idx = t + 256 * i;
        int nr = idx >> 4, kk = (idx & 15) * 8;
        *(s16x8*)&Bs[nr][kk] = *(const s16x8*)&BT[(size_t)nr * 128 + kk];
    }
    __syncthreads();
    f32x4 acc[4][3] = {};
#pragma unroll
    for (int kc = 0; kc < 4; kc++) {
        s16x8 af[4], bfr[3];
#pragma unroll
        for (int mt = 0; mt < 4; mt++) af[mt] = *(const s16x8*)&As[wm + mt * 16 + m16][kc * 32 + quad * 8];
#pragma unroll
        for (int nt = 0; nt < 3; nt++) bfr[nt] = *(const s16x8*)&Bs[wn + nt * 16 + m16][kc * 32 + quad * 8];
#pragma unroll
        for (int mt = 0; mt < 4; mt++)
#pragma unroll
            for (int nt = 0; nt < 3; nt++)
                acc[mt][nt] = __builtin_amdgcn_mfma_f32_16x16x32_bf16(af[mt], bfr[nt], acc[mt][nt], 0, 0, 0);
    }
#pragma unroll
    for (int mt = 0; mt < 4; mt++)
#pragma unroll
        for (int r4 = 0; r4 < 4; r4++) {
            int row = bm + wm + mt * 16 + quad * 4 + r4;
#pragma unroll
            for (int nt = 0; nt < 3; nt++)
                H[(size_t)row * 96 + wn + nt * 16 + m16] = f2bf(acc[mt][nt][r4]);
        }
}

// ---------------- gather 96 dims + GraphNorm2 fused: block = 1 graph (64 nodes) ----------------
__global__ __launch_bounds__(256) void gather_gn2(const short* __restrict__ H, const int* __restrict__ offs,
                                                  const int2* __restrict__ edg,
                                                  const float* __restrict__ ri,
                                                  const float* __restrict__ alpha, const float* __restrict__ gamma,
                                                  const float* __restrict__ beta, short* __restrict__ Outp) {
    __shared__ float sm[64 * 96];
    __shared__ float sscale[96], sshift[96];
    const int g = blockIdx.x;
    const int wave = threadIdx.x >> 6, lane = threadIdx.x & 63;
    const int e = lane >> 4, c = lane & 15;
    for (int nl = wave * 16; nl < wave * 16 + 16; nl++) {
        const int node = g * 64 + nl;
        const int s0 = offs[node], s1 = offs[node + 1];
        float acc[6] = {};
        for (int j0 = s0; j0 < s1; j0 += 4) {
            int j = j0 + e;
            bool ok = j < s1;
            int2 pe = edg[ok ? j : s0];
            int s = pe.x;
            float w = ok ? __builtin_bit_cast(float, pe.y) : 0.f;
            const unsigned int* hp = (const unsigned int*)(H + (size_t)s * 96 + c * 6);
            unsigned int u0 = hp[0], u1 = hp[1], u2 = hp[2];
            acc[0] = fmaf(w, bf2f((short)(u0 & 0xffff)), acc[0]);
            acc[1] = fmaf(w, bf2f((short)(u0 >> 16)), acc[1]);
            acc[2] = fmaf(w, bf2f((short)(u1 & 0xffff)), acc[2]);
            acc[3] = fmaf(w, bf2f((short)(u1 >> 16)), acc[3]);
            acc[4] = fmaf(w, bf2f((short)(u2 & 0xffff)), acc[4]);
            acc[5] = fmaf(w, bf2f((short)(u2 >> 16)), acc[5]);
        }
#pragma unroll
        for (int off = 16; off <= 32; off <<= 1)
#pragma unroll
            for (int k = 0; k < 6; k++) acc[k] += __shfl_xor(acc[k], off);
        if (e == 0) {
            float rv = ri[node];
#pragma unroll
            for (int k = 0; k < 6; k++) sm[nl * 96 + c * 6 + k] = lrelu(acc[k] * rv);
        }
    }
    __syncthreads();
    if (threadIdx.x < 96) {
        int cch = threadIdx.x;
        float s1v = 0.f, s2v = 0.f;
#pragma unroll 4
        for (int i = 0; i < 64; i++) { float v = sm[i * 96 + cch]; s1v += v; s2v += v * v; }
        float m = s1v * (1.f / 64.f);
        float a = alpha[cch];
        float var = s2v * (1.f / 64.f) - m * m * a * (2.f - a);
        float sc = gamma[cch] * rsqrtf(var + 1e-5f);
        sscale[cch] = sc;
        sshift[cch] = beta[cch] - sc * a * m;
    }
    __syncthreads();
#pragma unroll
    for (int i = 0; i < 6; i++) {
        int q = threadIdx.x + 256 * i;       // 0..1535
        int nl = q / 24, cq = (q % 24) * 4;
        s16x4 o;
#pragma unroll
        for (int k = 0; k < 4; k++) o[k] = f2bf(sscale[cq + k] * sm[nl * 96 + cq + k] + sshift[cq + k]);
        *(s16x4*)&Outp[(size_t)(g * 64 + nl) * 96 + cq] = o;
    }
}

// ---------------- W fp32 (R x Cc) -> WT bf16 (Cc x R), tiled transpose+convert ----------------
__global__ __launch_bounds__(256) void transp_cvt(const float* __restrict__ W, short* __restrict__ WT,
                                                  int R, int Cc) {
    __shared__ short tile[32][33];
    const int bc = blockIdx.x * 32;   // col of W
    const int br = blockIdx.y * 32;   // row of W
    const int tx = threadIdx.x & 31, ty = threadIdx.x >> 5;   // 32 x 8
#pragma unroll
    for (int i = 0; i < 32; i += 8)
        tile[ty + i][tx] = f2bf(W[(size_t)(br + ty + i) * Cc + bc + tx]);
    __syncthreads();
#pragma unroll
    for (int i = 0; i < 32; i += 8)
        WT[(size_t)(bc + ty + i) * R + br + tx] = tile[tx][ty + i];
}

// ---------------- MLP1: bf16 MFMA GEMM 4096x2048x6144 (global_load_lds BK=64, XOR-swizzled LDS) ----------------
__global__ __launch_bounds__(256) void mlp1_mfma(const short* __restrict__ A, const short* __restrict__ BT,
                                                 float* __restrict__ C) {
    constexpr int K = INMLP, Nn = HID;
    __shared__ short As[128 * 64];
    __shared__ short Bs[128 * 64];
    const int t = threadIdx.x;
    const int bm = blockIdx.x * 128, bn = blockIdx.y * 128;
    const int wave = t >> 6, lane = t & 63;
    const int wm = (wave & 1) * 64, wn = (wave >> 1) * 64;
    const int m16 = lane & 15, quad = lane >> 4;
    const int lrow = lane >> 3, lcol = lane & 7;
    const int scol = lcol ^ (lrow & 7);        // swizzled fetch chunk
    const int xkey = m16 & 7;                  // read-side unswizzle key
    f32x4 acc[4][4] = {};
    for (int k0 = 0; k0 < K; k0 += 64) {
#pragma unroll
        for (int j = 0; j < 4; j++) {
            const int rbase = 32 * wave + 8 * j;   // wave-uniform
            async16(&A[(size_t)(bm + rbase + lrow) * K + k0 + scol * 8], &As[rbase * 64]);
            async16(&BT[(size_t)(bn + rbase + lrow) * K + k0 + scol * 8], &Bs[rbase * 64]);
        }
        __syncthreads();
#pragma unroll
        for (int kc = 0; kc < 2; kc++) {
            s16x8 af[4], bfr[4];
#pragma unroll
            for (int mt = 0; mt < 4; mt++)
                af[mt] = *(const s16x8*)&As[(wm + mt * 16 + m16) * 64 + (((kc * 4 + quad) ^ xkey)) * 8];
#pragma unroll
            for (int nt = 0; nt < 4; nt++)
                bfr[nt] = *(const s16x8*)&Bs[(wn + nt * 16 + m16) * 64 + (((kc * 4 + quad) ^ xkey)) * 8];
#pragma unroll
            for (int mt = 0; mt < 4; mt++)
#pragma unroll
                for (int nt = 0; nt < 4; nt++)
                    acc[mt][nt] = __builtin_amdgcn_mfma_f32_16x16x32_bf16(af[mt], bfr[nt], acc[mt][nt], 0, 0, 0);
        }
        __syncthreads();
    }
#pragma unroll
    for (int mt = 0; mt < 4; mt++)
#pragma unroll
        for (int nt = 0; nt < 4; nt++)
#pragma unroll
            for (int r4 = 0; r4 < 4; r4++) {
                int row = bm + wm + mt * 16 + quad * 4 + r4;
                int col = bn + wn + nt * 16 + m16;
                C[(size_t)row * Nn + col] = lrelu(acc[mt][nt][r4]);
            }
}

// ---------------- generic MFMA GEMM: A fp32 (converted on stage), BT bf16, C fp32 ----------------
template <bool LEAKY>
__global__ __launch_bounds__(256) void mfma_gemm_af32(const float* __restrict__ A, const short* __restrict__ BT,
                                                      float* __restrict__ C, int M, int Nn, int K) {
    __shared__ short As[64][40];
    __shared__ short Bs[64][40];
    const int t = threadIdx.x;
    const int bm = blockIdx.x * 64, bn = blockIdx.y * 64;
    const int wave = t >> 6, lane = t & 63;
    const int wm = (wave & 1) * 32, wn = (wave >> 1) * 32;
    const int m16 = lane & 15, quad = lane >> 4;
    const int rr = t >> 2, kk = (t & 3) * 8;
    f32x4 acc[2][2] = {};
    for (int k0 = 0; k0 < K; k0 += 32) {
        const float* ap = &A[(size_t)(bm + rr) * K + k0 + kk];
        float4 v0 = *(const float4*)ap;
        float4 v1 = *(const float4*)(ap + 4);
        s16x8 a8;
        a8[0] = f2bf(v0.x); a8[1] = f2bf(v0.y); a8[2] = f2bf(v0.z); a8[3] = f2bf(v0.w);
        a8[4] = f2bf(v1.x); a8[5] = f2bf(v1.y); a8[6] = f2bf(v1.z); a8[7] = f2bf(v1.w);
        *(s16x8*)&As[rr][kk] = a8;
        *(s16x8*)&Bs[rr][kk] = *(const s16x8*)&BT[(size_t)(bn + rr) * K + k0 + kk];
        __syncthreads();
        s16x8 af[2], bfr[2];
#pragma unroll
        for (int mt = 0; mt < 2; mt++) af[mt] = *(const s16x8*)&As[wm + mt * 16 + m16][quad * 8];
#pragma unroll
        for (int nt = 0; nt < 2; nt++) bfr[nt] = *(const s16x8*)&Bs[wn + nt * 16 + m16][quad * 8];
#pragma unroll
        for (int mt = 0; mt < 2; mt++)
#pragma unroll
            for (int nt = 0; nt < 2; nt++)
                acc[mt][nt] = __builtin_amdgcn_mfma_f32_16x16x32_bf16(af[mt], bfr[nt], acc[mt][nt], 0, 0, 0);
        __syncthreads();
    }
#pragma unroll
    for (int mt = 0; mt < 2; mt++)
#pragma unroll
        for (int nt = 0; nt < 2; nt++)
#pragma unroll
            for (int r4 = 0; r4 < 4; r4++) {
                int row = bm + wm + mt * 16 + quad * 4 + r4;
                int col = bn + wn + nt * 16 + m16;
                float v = acc[mt][nt][r4];
                if (LEAKY) v = lrelu(v);
                C[(size_t)row * Nn + col] = v;
            }
}

// ---------------- per-row InstanceNorm (in place, fp32) ----------------
template <int NC>
__global__ __launch_bounds__(256) void rownorm(float* __restrict__ Y) {
    float* p = Y + (size_t)blockIdx.x * NC;
    float s1 = 0.f, s2 = 0.f;
    for (int c = threadIdx.x; c < NC; c += 256) { float v = p[c]; s1 += v; s2 += v * v; }
#pragma unroll
    for (int o = 32; o > 0; o >>= 1) { s1 += __shfl_down(s1, o); s2 += __shfl_down(s2, o); }
    __shared__ float w1[4], w2[4];
    if ((threadIdx.x & 63) == 0) { w1[threadIdx.x >> 6] = s1; w2[threadIdx.x >> 6] = s2; }
    __syncthreads();
    s1 = w1[0] + w1[1] + w1[2] + w1[3];
    s2 = w2[0] + w2[1] + w2[2] + w2[3];
    float m = s1 * (1.f / NC);
    float inv = rsqrtf(s2 * (1.f / NC) - m * m + 1e-5f);
    for (int c = threadIdx.x; c < NC; c += 256) p[c] = (p[c] - m) * inv;
}

extern "C" void kernel_launch(void* const* d_in, const int* in_sizes, int n_in,
                              void* d_out, int out_size, void* d_ws, size_t ws_size,
                              hipStream_t stream) {
    const float* x    = (const float*)d_in[0];
    const float* ew   = (const float*)d_in[1];
    const int*   src  = (const int*)d_in[2];
    const int*   dst  = (const int*)d_in[3];
    const float* W1   = (const float*)d_in[4];
    const float* W2   = (const float*)d_in[5];
    const float* a1   = (const float*)d_in[6];
    const float* g1   = (const float*)d_in[7];
    const float* b1   = (const float*)d_in[8];
    const float* a2   = (const float*)d_in[9];
    const float* g2   = (const float*)d_in[10];
    const float* b2   = (const float*)d_in[11];
    const float* Win  = (const float*)d_in[12];
    const float* Whid = (const float*)d_in[13];
    const float* Wcls = (const float*)d_in[14];
    float* out = (float*)d_out;

    // ---- workspace layout (~141 MB fixed) ----
    float* ro   = (float*)d_ws;                    // NN
    float* ri   = ro + NN;                         // NN
    int*   din  = (int*)(ri + NN);                 // NN (deg_in for scan)
    int*   offs = din + NN;                        // NN+4
    int*   blks = offs + NN + 4;                   // 256
    short* w1t  = (short*)(blks + 256);            // 128*64 bf16
    short* w2t  = w1t + 128 * 64;                  // 96*128 bf16
    int2*  edg  = (int2*)(((size_t)(w2t + 96 * 128) + 15) & ~(size_t)15);   // EE int2 (src, ew*ro)
    short* Abf  = (short*)(edg + EE);              // NN*128 bf16 region
    short* Bbf  = Abf + (size_t)NN * 128;          // NN*128 bf16 region
    short* xbf  = Abf;                             // NN*64
    short* aggx = Abf + (size_t)NN * 64;           // NN*64
    // graph-build temps overlaid into Abf region (dead until cvt_x): 32 MB
    unsigned* din_r    = (unsigned*)Abf;           // 8*NN
    unsigned* dout_r   = din_r + 8 * NN;           // 8*NN
    int*      repbase  = (int*)(dout_r + 8 * NN);  // 8*NN
    unsigned* rankpack = (unsigned*)(repbase + 8 * NN);  // EE
    // overlays into Abf region after gather_gn2 (h2 dead):
    short* WinT = Abf;                                                  // 2048*6144 bf16 = 25165824 B
    float* D    = (float*)((char*)Abf + 25165824);                      // 4096*2048 fp32 = 33554432 B
    float* Y2   = (float*)((char*)Abf + 25165824 + 33554432);           // 4096*512 fp32  =  8388608 B
    // overlays into Bbf region after mlp1_mfma consumes it:
    short* WhidT = Bbf;                            // 512*2048 bf16
    short* WclsT = WhidT + (size_t)HID4 * HID;     // 256*512 bf16

    // 1) degrees via XCD-replicated L2-local atomics (+ per-edge rank capture)
    hipMemsetAsync(din_r, 0, 16 * NN * sizeof(unsigned), stream);   // din_r + dout_r
    count_deg<<<EE / 256, 256, 0, stream>>>(src, dst, dout_r, din_r, rankpack);
    deg_reduce<<<NN / 256, 256, 0, stream>>>(din_r, dout_r, repbase, ro, ri, din);

    // 2) CSR by dst: scan + atomic-free fill
    scanA<<<NN / 1024, 256, 0, stream>>>(din, blks);
    scanB<<<1, 256, 0, stream>>>(blks, offs + NN);
    scanC<<<NN / 1024, 256, 0, stream>>>(din, blks, offs);
    fill_csr<<<EE / 256, 256, 0, stream>>>(src, dst, ew, ro, offs, repbase, rankpack, edg);

    // 3) conv layer 1: gather x (64 dims), then GEMM + fused GraphNorm1
    cvt_x<<<NN * 64 / 1024, 256, 0, stream>>>(x, xbf);
    transp_cvt<<<dim3(128 / 32, 64 / 32), 256, 0, stream>>>(W1, w1t, 64, 128);
    gather64<<<NN / 4, 256, 0, stream>>>(xbf, offs, edg, aggx);
    conv1_gn<<<NN / 128, 256, 0, stream>>>(aggx, w1t, ri, a1, g1, b1, Bbf);   // Bbf = gn1

    // 4) conv layer 2: GEMM, then fused gather + GraphNorm2
    transp_cvt<<<dim3(96 / 32, 128 / 32), 256, 0, stream>>>(W2, w2t, 128, 96);
    conv2_mfma<<<NN / 128, 256, 0, stream>>>(Bbf, w2t, Abf);                  // h2 (xbf/aggx dead)
    gather_gn2<<<BB, 256, 0, stream>>>(Abf, offs, edg, ri, a2, g2, b2, Bbf);  // Bbf = gn2 (MLP input)

    // 5) MLP
    transp_cvt<<<dim3(HID / 32, INMLP / 32), 256, 0, stream>>>(Win, WinT, INMLP, HID);
    mlp1_mfma<<<dim3(BB / 128, HID / 128), 256, 0, stream>>>(Bbf, WinT, D);
    transp_cvt<<<dim3(HID4 / 32, HID / 32), 256, 0, stream>>>(Whid, WhidT, HID, HID4);
    transp_cvt<<<dim3(OUTF / 32, HID4 / 32), 256, 0, stream>>>(Wcls, WclsT, HID4, OUTF);
    rownorm<HID><<<BB, 256, 0, stream>>>(D);
    mfma_gemm_af32<true><<<dim3(BB / 64, HID4 / 64), 256, 0, stream>>>(D, WhidT, Y2, BB, HID4, HID);
    rownorm<HID4><<<BB, 256, 0, stream>>>(Y2);
    mfma_gemm_af32<false><<<dim3(BB / 64, OUTF / 64), 256, 0, stream>>>(Y2, WclsT, out, BB, OUTF, HID4);
}